// Round 7
// baseline (477.166 us; speedup 1.0000x reference)
//
#include <hip/hip_runtime.h>
#include <math.h>

typedef __attribute__((ext_vector_type(8))) short s16x8;   // 8 bf16 (4 VGPRs)
typedef __attribute__((ext_vector_type(4))) float f32x4;   // MFMA C/D

// Problem constants
#define B_    4
#define C_    64
#define S_    32768          // 32*32*32 spatial
#define N_    131072         // B_*S_ tokens
#define K_    512            // codebook size
#define SPLITS 8             // blocks per code in k_dw_split
#define DECAY_ 0.99f
#define ONEM_  0.01f
#define ALPHA_ 1e-5f
#define DELTA_ 0.05f         // ambiguity margin >> MFMA-emulation error bound

// d_out layout (float32, concatenated in reference return order)
#define OFF_LOSS 0
#define OFF_Q    1
#define OFF_PERP 8388609
#define OFF_IDX  8388610
#define OFF_NEMB 8519682
#define OFF_NCS  8552450
#define OFF_NEA  8552962

// ws layout in 4-byte units.
// WS_SPL spans [395792, 444944) — 3*512*64 bf16 = 49152 DWORDS.
// WS_AMB must start AFTER it (R6 bug: 420368 overlapped the split table,
// k_assign's ambiguous-list writes corrupted B operands mid-kernel -> inf).
// High-water 576016 dwords = 2.25 MB (< R4's working 2.51 MB).
#define WS_LOSS   0         // [0] loss accum
#define WS_AMBN   8         // [8] ambiguous-token count
#define WS_CNT    16        // 512 ints
#define WS_CUR    528       // 512 ints
#define WS_OFFS   1040      // 512 ints
#define WS_SMOOTH 1552      // 512 floats
#define WS_E2     2064      // 512 floats (||e||^2)
#define WS_SORT   2576      // 131072 ints
#define WS_PART   133648    // 8*512*64 floats -> ends 395792
#define WS_SPL    395792    // 49152 dwords (bf16 x3 table) -> ends 444944
#define WS_AMB    444944    // up to 131072 ints -> ends 576016

__device__ __forceinline__ ushort f2bf(float f) {           // RNE fp32 -> bf16
    uint u = __float_as_uint(f);
    u = u + 0x7FFFu + ((u >> 16) & 1u);
    return (ushort)(u >> 16);
}
__device__ __forceinline__ float bf2f(ushort h) {
    return __uint_as_float(((uint)h) << 16);
}

// ---------------------------------------------------------------------------
// K0: split table. B' = -2*embed as 3 bf16 terms, plus ||e||^2 per code.
// ---------------------------------------------------------------------------
__global__ __launch_bounds__(256) void k_split(const float* __restrict__ embed,
                                               float* __restrict__ wsf) {
    const int t = threadIdx.x;
    const int lane = t & 63;
    const int code = blockIdx.x * 4 + (t >> 6);
    const float e = embed[code * C_ + lane];
    const float sc = -2.f * e;
    const ushort h1 = f2bf(sc);
    const float r1 = sc - bf2f(h1);
    const ushort h2 = f2bf(r1);
    const float r2 = r1 - bf2f(h2);
    const ushort h3 = f2bf(r2);
    ushort* tab = (ushort*)(wsf + WS_SPL);
    tab[0 * (K_ * C_) + code * C_ + lane] = h1;
    tab[1 * (K_ * C_) + code * C_ + lane] = h2;
    tab[2 * (K_ * C_) + code * C_ + lane] = h3;
    float sq = e * e;
    for (int o = 32; o > 0; o >>= 1) sq += __shfl_down(sq, o, 64);
    if (lane == 0) wsf[WS_E2 + code] = sq;
}

// ---------------------------------------------------------------------------
// K1: MFMA argmin with runner-up tracking. Wave owns 16 tokens x 512 codes
//     (32 tiles of 16x16x32 bf16, 12 MFMA = 6-term fp32 emulation, -2 folded
//     into B). Gap < DELTA_ => token pushed to ambiguous list for exact
//     rescore. Writes flat_x (channel-last) + idx + loss. No histogram here.
// ---------------------------------------------------------------------------
__global__ __launch_bounds__(256) void k_assign(const float* __restrict__ in,
                                                float* __restrict__ out,
                                                float* __restrict__ wsf,
                                                int* __restrict__ wsi) {
    __shared__ float s_e2l[K_];
    __shared__ float s_x2[64];
    __shared__ float s_loss;

    const int t = threadIdx.x;
    const int lane = t & 63;
    const int w = t >> 6;
    const int col = lane & 15;       // A: token row m; B/C: code col n
    const int quad = lane >> 4;      // k-chunk for A/B; row-group for C/D

    for (int i = t; i < K_; i += 256) s_e2l[i] = wsf[WS_E2 + i];
    if (t == 0) s_loss = 0.f;

    const int n0 = blockIdx.x * 64 + w * 16;  // wave's token base
    const int n  = n0 + col;                  // this lane's A-token
    const int b  = n >> 15;
    const int s  = n & (S_ - 1);
    const int base = (b << 21) + s;

    float x0[8], x1[8];
#pragma unroll
    for (int j = 0; j < 8; ++j) {
        x0[j] = in[base + ((quad * 8 + j) << 15)];
        x1[j] = in[base + ((32 + quad * 8 + j) << 15)];
    }
    float x2 = 0.f;
#pragma unroll
    for (int j = 0; j < 8; ++j) x2 += x0[j] * x0[j] + x1[j] * x1[j];
    x2 += __shfl_xor(x2, 16, 64);
    x2 += __shfl_xor(x2, 32, 64);
    if (quad == 0) s_x2[w * 16 + col] = x2;

    // 3-way bf16 split of x (A side), both k-tiles
    s16x8 a1_0, a2_0, a3_0, a1_1, a2_1, a3_1;
#pragma unroll
    for (int j = 0; j < 8; ++j) {
        ushort h = f2bf(x0[j]); a1_0[j] = (short)h;
        float r = x0[j] - bf2f(h);
        h = f2bf(r); a2_0[j] = (short)h;
        r = r - bf2f(h);
        a3_0[j] = (short)f2bf(r);
        h = f2bf(x1[j]); a1_1[j] = (short)h;
        r = x1[j] - bf2f(h);
        h = f2bf(r); a2_1[j] = (short)h;
        r = r - bf2f(h);
        a3_1[j] = (short)f2bf(r);
    }
    __syncthreads();

    const s16x8* tab = (const s16x8*)(wsf + WS_SPL);
    float bestd[4]  = {3.4e38f, 3.4e38f, 3.4e38f, 3.4e38f};
    float bestd2[4] = {3.4e38f, 3.4e38f, 3.4e38f, 3.4e38f};
    int   besti[4]  = {0, 0, 0, 0};

    for (int ct = 0; ct < 32; ++ct) {
        const int code0 = ct * 16;
        const float e2c = s_e2l[code0 + col];
        const int o = (code0 + col) * 8 + quad;
        s16x8 b1_0 = tab[o];            s16x8 b1_1 = tab[o + 4];
        s16x8 b2_0 = tab[4096 + o];     s16x8 b2_1 = tab[4096 + o + 4];
        s16x8 b3_0 = tab[8192 + o];     s16x8 b3_1 = tab[8192 + o + 4];
        f32x4 acc = {e2c, e2c, e2c, e2c};
        acc = __builtin_amdgcn_mfma_f32_16x16x32_bf16(a3_0, b1_0, acc, 0, 0, 0);
        acc = __builtin_amdgcn_mfma_f32_16x16x32_bf16(a3_1, b1_1, acc, 0, 0, 0);
        acc = __builtin_amdgcn_mfma_f32_16x16x32_bf16(a2_0, b2_0, acc, 0, 0, 0);
        acc = __builtin_amdgcn_mfma_f32_16x16x32_bf16(a2_1, b2_1, acc, 0, 0, 0);
        acc = __builtin_amdgcn_mfma_f32_16x16x32_bf16(a1_0, b3_0, acc, 0, 0, 0);
        acc = __builtin_amdgcn_mfma_f32_16x16x32_bf16(a1_1, b3_1, acc, 0, 0, 0);
        acc = __builtin_amdgcn_mfma_f32_16x16x32_bf16(a2_0, b1_0, acc, 0, 0, 0);
        acc = __builtin_amdgcn_mfma_f32_16x16x32_bf16(a2_1, b1_1, acc, 0, 0, 0);
        acc = __builtin_amdgcn_mfma_f32_16x16x32_bf16(a1_0, b2_0, acc, 0, 0, 0);
        acc = __builtin_amdgcn_mfma_f32_16x16x32_bf16(a1_1, b2_1, acc, 0, 0, 0);
        acc = __builtin_amdgcn_mfma_f32_16x16x32_bf16(a1_0, b1_0, acc, 0, 0, 0);
        acc = __builtin_amdgcn_mfma_f32_16x16x32_bf16(a1_1, b1_1, acc, 0, 0, 0);
#pragma unroll
        for (int r = 0; r < 4; ++r) {
            const float a = acc[r];
            if (a < bestd[r]) {
                bestd2[r] = bestd[r]; bestd[r] = a; besti[r] = code0 + col;
            } else if (a < bestd2[r]) {
                bestd2[r] = a;
            }
        }
    }

    // cross-lane merge of (d1,i1,d2) within each 16-lane group
#pragma unroll
    for (int r = 0; r < 4; ++r) {
        float d1 = bestd[r], d2 = bestd2[r]; int i1 = besti[r];
        for (int m = 1; m <= 8; m <<= 1) {
            const float d1o = __shfl_xor(d1, m, 64);
            const int   i1o = __shfl_xor(i1, m, 64);
            const float d2o = __shfl_xor(d2, m, 64);
            if (d1o < d1 || (d1o == d1 && i1o < i1)) {
                d2 = fminf(d1, d2o); d1 = d1o; i1 = i1o;
            } else {
                d2 = fminf(d2, d1o);
            }
        }
        bestd[r] = d1; bestd2[r] = d2; besti[r] = i1;
    }

    // flat_x rows (channel-last) into the quantized region
    {
        float4* q0 = (float4*)(out + OFF_Q + (size_t)n * C_ + quad * 8);
        q0[0] = make_float4(x0[0], x0[1], x0[2], x0[3]);
        q0[1] = make_float4(x0[4], x0[5], x0[6], x0[7]);
        float4* q1 = (float4*)(out + OFF_Q + (size_t)n * C_ + 32 + quad * 8);
        q1[0] = make_float4(x1[0], x1[1], x1[2], x1[3]);
        q1[1] = make_float4(x1[4], x1[5], x1[6], x1[7]);
    }

    if (col == 0) {                   // writer lanes: one per quad per wave
        float lsum = 0.f;
#pragma unroll
        for (int r = 0; r < 4; ++r) {
            const int tok = quad * 4 + r;               // C/D row = quad*4+reg
            out[OFF_IDX + n0 + tok] = (float)besti[r];
            lsum += bestd[r] + s_x2[w * 16 + tok];      // x2 for loss only
            if (bestd2[r] - bestd[r] < DELTA_) {        // near-tie: exact rescore
                const int pos = atomicAdd(&wsi[WS_AMBN], 1);
                wsi[WS_AMB + pos] = n0 + tok;
            }
        }
        atomicAdd(&s_loss, lsum);
    }
    __syncthreads();
    if (t == 0) atomicAdd(&wsf[WS_LOSS], s_loss);
}

// ---------------------------------------------------------------------------
// K1b: exact fp32 rescore of ambiguous tokens (one wave per token; lane l
//      handles codes l, l+64, ..., l+448; R1-style 4-way partial dots).
// ---------------------------------------------------------------------------
__global__ __launch_bounds__(256) void k_fixup(const float* __restrict__ embed,
                                               float* __restrict__ out,
                                               const float* __restrict__ wsf,
                                               const int* __restrict__ wsi) {
    __shared__ float sx[4][C_];
    const int t = threadIdx.x;
    const int lane = t & 63;
    const int w = t >> 6;
    const int gw = blockIdx.x * 4 + w;
    const int nw = gridDim.x * 4;
    const int cntA = wsi[WS_AMBN];

    for (int a = gw; a < cntA; a += nw) {
        const int n = wsi[WS_AMB + a];
        const float xv = out[OFF_Q + (size_t)n * C_ + lane];  // flat_x row
        sx[w][lane] = xv;
        float x2 = xv * xv;
        for (int m = 1; m <= 32; m <<= 1) x2 += __shfl_xor(x2, m, 64);

        float bd = 3.4e38f; int bi = 0;
        for (int q = 0; q < 8; ++q) {
            const int k = lane + (q << 6);               // ascending per lane
            const float* e = embed + k * C_;
            float d0 = 0.f, d1 = 0.f, d2 = 0.f, d3 = 0.f;
#pragma unroll
            for (int c = 0; c < C_; c += 4) {
                d0 += sx[w][c + 0] * e[c + 0];
                d1 += sx[w][c + 1] * e[c + 1];
                d2 += sx[w][c + 2] * e[c + 2];
                d3 += sx[w][c + 3] * e[c + 3];
            }
            const float dist = x2 + wsf[WS_E2 + k] - 2.f * ((d0 + d1) + (d2 + d3));
            if (dist < bd) { bd = dist; bi = k; }
        }
        for (int m = 1; m <= 32; m <<= 1) {
            const float db = __shfl_xor(bd, m, 64);
            const int   ib = __shfl_xor(bi, m, 64);
            if (db < bd || (db == bd && ib < bi)) { bd = db; bi = ib; }
        }
        if (lane == 0) out[OFF_IDX + n] = (float)bi;
    }
}

// ---------------------------------------------------------------------------
// K1c: histogram of (post-fixup) indices, LDS-privatized.
// ---------------------------------------------------------------------------
__global__ __launch_bounds__(256) void k_hist(const float* __restrict__ out,
                                              int* __restrict__ wsi) {
    __shared__ int hc[K_];
    const int t = threadIdx.x;
    for (int i = t; i < K_; i += 256) hc[i] = 0;
    __syncthreads();
    const int n = blockIdx.x * 256 + t;
    atomicAdd(&hc[(int)out[OFF_IDX + n]], 1);
    __syncthreads();
    for (int i = t; i < K_; i += 256) {
        const int v = hc[i];
        if (v) atomicAdd(&wsi[WS_CNT + i], v);
    }
}

// ---------------------------------------------------------------------------
// K2: single block, 512 threads. new_cluster_size, n, perplexity, smoothed,
//     exclusive prefix sum of counts, loss finalize.
// ---------------------------------------------------------------------------
__global__ __launch_bounds__(512) void k_stats(const float* __restrict__ cs,
                                               float* __restrict__ out,
                                               float* __restrict__ wsf,
                                               int* __restrict__ wsi) {
    __shared__ float sf[K_];
    __shared__ int   si[K_];
    const int t = threadIdx.x;

    const int cnt = wsi[WS_CNT + t];
    const float ncs = cs[t] * DECAY_ + ONEM_ * (float)cnt;
    out[OFF_NCS + t] = ncs;

    sf[t] = ncs;
    __syncthreads();
    for (int o = 256; o > 0; o >>= 1) {
        if (t < o) sf[t] += sf[t + o];
        __syncthreads();
    }
    const float n = sf[0];
    __syncthreads();

    const float ap = (float)cnt / (float)N_;
    sf[t] = ap * logf(ap + 1e-10f);
    __syncthreads();
    for (int o = 256; o > 0; o >>= 1) {
        if (t < o) sf[t] += sf[t + o];
        __syncthreads();
    }
    if (t == 0) {
        out[OFF_PERP] = expf(-sf[0]);
        out[OFF_LOSS] = 0.25f * wsf[WS_LOSS] / (float)((long long)N_ * C_);
    }

    wsf[WS_SMOOTH + t] = n * (ncs + ALPHA_) / (n + (float)K_ * ALPHA_);

    si[t] = cnt;
    __syncthreads();
    for (int o = 1; o < K_; o <<= 1) {
        int v = (t >= o) ? si[t - o] : 0;
        __syncthreads();
        si[t] += v;
        __syncthreads();
    }
    wsi[WS_OFFS + t] = si[t] - cnt;
}

// ---------------------------------------------------------------------------
// K3: counting-sort scatter of token ids by code.
// ---------------------------------------------------------------------------
__global__ __launch_bounds__(256) void k_scatter(const float* __restrict__ out,
                                                 int* __restrict__ wsi) {
    const int n = blockIdx.x * 256 + threadIdx.x;
    const int k = (int)out[OFF_IDX + n];
    const int pos = atomicAdd(&wsi[WS_CUR + k], 1);
    wsi[WS_SORT + wsi[WS_OFFS + k] + pos] = n;
}

// ---------------------------------------------------------------------------
// K4: dw partials. Grid = K_*SPLITS one-wave blocks; ids bulk-loaded +
//     shfl-broadcast; row gathers 4 deep; plain coalesced partial stores.
// ---------------------------------------------------------------------------
__global__ __launch_bounds__(64) void k_dw_split(float* __restrict__ out,
                                                 float* __restrict__ wsf,
                                                 const int* __restrict__ wsi) {
    const int lane = threadIdx.x;                 // == channel c
    const int k = blockIdx.x >> 3;
    const int p = blockIdx.x & (SPLITS - 1);
    const int off = wsi[WS_OFFS + k];
    const int cnt = wsi[WS_CNT + k];
    const int chunk = (cnt + SPLITS - 1) >> 3;
    const int j0 = p * chunk;
    const int j1 = min(j0 + chunk, cnt);
    const float* fx = out + OFF_Q;
    const int* sort = wsi + WS_SORT + off;

    float acc = 0.f;
    for (int base = j0; base < j1; base += 64) {
        const int mcnt = min(64, j1 - base);
        int id = 0;
        if (base + lane < j1) id = sort[base + lane];
        int m = 0;
        for (; m + 4 <= mcnt; m += 4) {
            const int t0 = __shfl(id, m + 0, 64);
            const int t1 = __shfl(id, m + 1, 64);
            const int t2 = __shfl(id, m + 2, 64);
            const int t3 = __shfl(id, m + 3, 64);
            const float v0 = fx[(size_t)t0 * C_ + lane];
            const float v1 = fx[(size_t)t1 * C_ + lane];
            const float v2 = fx[(size_t)t2 * C_ + lane];
            const float v3 = fx[(size_t)t3 * C_ + lane];
            acc += (v0 + v1) + (v2 + v3);
        }
        for (; m < mcnt; ++m) {
            const int tk = __shfl(id, m, 64);
            acc += fx[(size_t)tk * C_ + lane];
        }
    }
    wsf[WS_PART + (size_t)blockIdx.x * C_ + lane] = acc;
}

// ---------------------------------------------------------------------------
// K5: reduce SPLITS partials -> dw, then EMA outputs.
// ---------------------------------------------------------------------------
__global__ __launch_bounds__(256) void k_ema(const float* __restrict__ embed_avg,
                                             float* __restrict__ out,
                                             const float* __restrict__ wsf) {
    const int i = blockIdx.x * 256 + threadIdx.x;   // i = k*64 + c
    const int k = i >> 6;
    const int c = i & 63;
    float dw = 0.f;
#pragma unroll
    for (int p = 0; p < SPLITS; ++p)
        dw += wsf[WS_PART + (size_t)(k * SPLITS + p) * C_ + c];
    const float nea = embed_avg[i] * DECAY_ + ONEM_ * dw;
    out[OFF_NEA + i] = nea;
    out[OFF_NEMB + i] = nea / wsf[WS_SMOOTH + k];
}

// ---------------------------------------------------------------------------
// K6: rewrite the quantized region with embed[idx] in [B,C,S] layout.
// ---------------------------------------------------------------------------
__global__ __launch_bounds__(256) void k_quant(const float* __restrict__ embed,
                                               float* __restrict__ out) {
    const int t = threadIdx.x;
    const int n = blockIdx.x * 256 + t;
    const int b = n >> 15;
    const int s = n & (S_ - 1);
    const int base = (b << 21) + s;
    const int k = (int)out[OFF_IDX + n];
    const float4* er = (const float4*)(embed + k * C_);
#pragma unroll
    for (int q = 0; q < 16; ++q) {
        float4 v = er[q];
        out[OFF_Q + base + ((4*q + 0) << 15)] = v.x;
        out[OFF_Q + base + ((4*q + 1) << 15)] = v.y;
        out[OFF_Q + base + ((4*q + 2) << 15)] = v.z;
        out[OFF_Q + base + ((4*q + 3) << 15)] = v.w;
    }
}

extern "C" void kernel_launch(void* const* d_in, const int* in_sizes, int n_in,
                              void* d_out, int out_size, void* d_ws, size_t ws_size,
                              hipStream_t stream) {
    const float* in        = (const float*)d_in[0];
    const float* embed     = (const float*)d_in[1];
    const float* embed_avg = (const float*)d_in[2];
    const float* cs        = (const float*)d_in[3];
    float* out = (float*)d_out;
    float* wsf = (float*)d_ws;
    int*   wsi = (int*)d_ws;

    // zero: loss accum + ambig count + counts + cursors
    hipMemsetAsync(d_ws, 0, (WS_CUR + K_) * sizeof(int), stream);

    k_split   <<<K_ / 4, 256, 0, stream>>>(embed, wsf);
    k_assign  <<<N_ / 64, 256, 0, stream>>>(in, out, wsf, wsi);
    k_fixup   <<<128, 256, 0, stream>>>(embed, out, wsf, wsi);
    k_hist    <<<N_ / 256, 256, 0, stream>>>(out, wsi);
    k_stats   <<<1, K_, 0, stream>>>(cs, out, wsf, wsi);
    k_scatter <<<N_ / 256, 256, 0, stream>>>(out, wsi);
    k_dw_split<<<K_ * SPLITS, 64, 0, stream>>>(out, wsf, wsi);
    k_ema     <<<K_ * C_ / 256, 256, 0, stream>>>(embed_avg, out, wsf);
    k_quant   <<<N_ / 256, 256, 0, stream>>>(embed, out);
}

// Round 8
// 318.317 us; speedup vs baseline: 1.4990x; 1.4990x over previous
//
#include <hip/hip_runtime.h>
#include <math.h>

typedef __attribute__((ext_vector_type(8))) short s16x8;   // 8 bf16 (4 VGPRs)
typedef __attribute__((ext_vector_type(4))) float f32x4;   // MFMA C/D

// Problem constants
#define B_    4
#define C_    64
#define S_    32768          // 32*32*32 spatial
#define N_    131072         // B_*S_ tokens
#define K_    512            // codebook size
#define SPLITS 8             // blocks per code in k_dw_split
#define DECAY_ 0.99f
#define ONEM_  0.01f
#define ALPHA_ 1e-5f
#define DELTA_ 0.01f         // ambiguity margin >> ~2e-4 emulation error bound

// d_out layout (float32, concatenated in reference return order)
#define OFF_LOSS 0
#define OFF_Q    1
#define OFF_PERP 8388609
#define OFF_IDX  8388610
#define OFF_NEMB 8519682
#define OFF_NCS  8552450
#define OFF_NEA  8552962

// ws layout in 4-byte units (high-water 576016 dwords = 2.25 MB)
#define WS_LOSS   0         // [0] loss accum
#define WS_AMBN   8         // [8] ambiguous-token count
#define WS_CNT    16        // 512 ints
#define WS_CUR    528       // 512 ints
#define WS_OFFS   1040      // 512 ints
#define WS_SMOOTH 1552      // 512 floats
#define WS_E2     2064      // 512 floats (||e||^2)
#define WS_SORT   2576      // 131072 ints
#define WS_PART   133648    // 8*512*64 floats -> ends 395792
#define WS_SPL    395792    // 49152 dwords (bf16 x3 table) -> ends 444944
#define WS_AMB    444944    // up to 131072 ints -> ends 576016

__device__ __forceinline__ ushort f2bf(float f) {           // RNE fp32 -> bf16
    uint u = __float_as_uint(f);
    u = u + 0x7FFFu + ((u >> 16) & 1u);
    return (ushort)(u >> 16);
}
__device__ __forceinline__ float bf2f(ushort h) {
    return __uint_as_float(((uint)h) << 16);
}

// ---------------------------------------------------------------------------
// K0: split table. B' = -2*embed as 3 bf16 terms, plus ||e||^2 per code.
// ---------------------------------------------------------------------------
__global__ __launch_bounds__(256) void k_split(const float* __restrict__ embed,
                                               float* __restrict__ wsf) {
    const int t = threadIdx.x;
    const int lane = t & 63;
    const int code = blockIdx.x * 4 + (t >> 6);
    const float e = embed[code * C_ + lane];
    const float sc = -2.f * e;
    const ushort h1 = f2bf(sc);
    const float r1 = sc - bf2f(h1);
    const ushort h2 = f2bf(r1);
    const float r2 = r1 - bf2f(h2);
    const ushort h3 = f2bf(r2);
    ushort* tab = (ushort*)(wsf + WS_SPL);
    tab[0 * (K_ * C_) + code * C_ + lane] = h1;
    tab[1 * (K_ * C_) + code * C_ + lane] = h2;
    tab[2 * (K_ * C_) + code * C_ + lane] = h3;
    float sq = e * e;
    for (int o = 32; o > 0; o >>= 1) sq += __shfl_down(sq, o, 64);
    if (lane == 0) wsf[WS_E2 + code] = sq;
}

// ---------------------------------------------------------------------------
// K1: MFMA argmin, 4 A-sets per wave (64 tokens/wave, 256/block). One B-tile
//     load feeds 48 MFMAs (4 independent acc chains). Runner-up margin ->
//     ambiguous list. Writes flat_x + idx + LDS histogram + loss.
//     a[j][k]: k = 0:s1kt0 1:s1kt1 2:s2kt0 3:s2kt1 4:s3kt0 5:s3kt1
// ---------------------------------------------------------------------------
__global__ __launch_bounds__(256, 2) void k_assign(const float* __restrict__ in,
                                                   float* __restrict__ out,
                                                   float* __restrict__ wsf,
                                                   int* __restrict__ wsi) {
    __shared__ float s_e2l[K_];
    __shared__ int   s_cnt[K_];
    __shared__ float s_x2[256];
    __shared__ float s_loss;

    const int t = threadIdx.x;
    const int lane = t & 63;
    const int w = t >> 6;
    const int col = lane & 15;       // A row m / B,C col n
    const int quad = lane >> 4;      // k-chunk for A/B; row-group for C/D

    for (int i = t; i < K_; i += 256) { s_e2l[i] = wsf[WS_E2 + i]; s_cnt[i] = 0; }
    if (t == 0) s_loss = 0.f;

    const int nw = blockIdx.x * 256 + w * 64;   // wave token base (64 tokens)

    s16x8 a[4][6];
#pragma unroll
    for (int j = 0; j < 4; ++j) {
        const int n = nw + j * 16 + col;
        const int base = ((n >> 15) << 21) + (n & (S_ - 1));
        float x0[8], x1[8];
#pragma unroll
        for (int q = 0; q < 8; ++q) {
            x0[q] = in[base + ((quad * 8 + q) << 15)];
            x1[q] = in[base + ((32 + quad * 8 + q) << 15)];
        }
        float x2 = 0.f;
#pragma unroll
        for (int q = 0; q < 8; ++q) x2 += x0[q] * x0[q] + x1[q] * x1[q];
        x2 += __shfl_xor(x2, 16, 64);
        x2 += __shfl_xor(x2, 32, 64);
        if (quad == 0) s_x2[w * 64 + j * 16 + col] = x2;

        float4* q0 = (float4*)(out + OFF_Q + (size_t)n * C_ + quad * 8);
        q0[0] = make_float4(x0[0], x0[1], x0[2], x0[3]);
        q0[1] = make_float4(x0[4], x0[5], x0[6], x0[7]);
        float4* q1 = (float4*)(out + OFF_Q + (size_t)n * C_ + 32 + quad * 8);
        q1[0] = make_float4(x1[0], x1[1], x1[2], x1[3]);
        q1[1] = make_float4(x1[4], x1[5], x1[6], x1[7]);

#pragma unroll
        for (int q = 0; q < 8; ++q) {
            ushort h = f2bf(x0[q]); a[j][0][q] = (short)h;
            float r = x0[q] - bf2f(h);
            h = f2bf(r); a[j][2][q] = (short)h;
            r = r - bf2f(h);
            a[j][4][q] = (short)f2bf(r);
            h = f2bf(x1[q]); a[j][1][q] = (short)h;
            r = x1[q] - bf2f(h);
            h = f2bf(r); a[j][3][q] = (short)h;
            r = r - bf2f(h);
            a[j][5][q] = (short)f2bf(r);
        }
    }
    __syncthreads();

    const s16x8* tab = (const s16x8*)(wsf + WS_SPL);
    float bestd[4][4], bestd2[4][4];
    int   besti[4][4];
#pragma unroll
    for (int j = 0; j < 4; ++j)
#pragma unroll
        for (int r = 0; r < 4; ++r) { bestd[j][r] = 3.4e38f; bestd2[j][r] = 3.4e38f; besti[j][r] = 0; }

    for (int ct = 0; ct < 32; ++ct) {
        const int code0 = ct * 16;
        const float e2c = s_e2l[code0 + col];
        const int o = (code0 + col) * 8 + quad;
        const s16x8 b1_0 = tab[o];            const s16x8 b1_1 = tab[o + 4];
        const s16x8 b2_0 = tab[4096 + o];     const s16x8 b2_1 = tab[4096 + o + 4];
        const s16x8 b3_0 = tab[8192 + o];     const s16x8 b3_1 = tab[8192 + o + 4];
#pragma unroll
        for (int j = 0; j < 4; ++j) {
            f32x4 acc = {e2c, e2c, e2c, e2c};
            acc = __builtin_amdgcn_mfma_f32_16x16x32_bf16(a[j][4], b1_0, acc, 0, 0, 0);
            acc = __builtin_amdgcn_mfma_f32_16x16x32_bf16(a[j][5], b1_1, acc, 0, 0, 0);
            acc = __builtin_amdgcn_mfma_f32_16x16x32_bf16(a[j][2], b2_0, acc, 0, 0, 0);
            acc = __builtin_amdgcn_mfma_f32_16x16x32_bf16(a[j][3], b2_1, acc, 0, 0, 0);
            acc = __builtin_amdgcn_mfma_f32_16x16x32_bf16(a[j][0], b3_0, acc, 0, 0, 0);
            acc = __builtin_amdgcn_mfma_f32_16x16x32_bf16(a[j][1], b3_1, acc, 0, 0, 0);
            acc = __builtin_amdgcn_mfma_f32_16x16x32_bf16(a[j][2], b1_0, acc, 0, 0, 0);
            acc = __builtin_amdgcn_mfma_f32_16x16x32_bf16(a[j][3], b1_1, acc, 0, 0, 0);
            acc = __builtin_amdgcn_mfma_f32_16x16x32_bf16(a[j][0], b2_0, acc, 0, 0, 0);
            acc = __builtin_amdgcn_mfma_f32_16x16x32_bf16(a[j][1], b2_1, acc, 0, 0, 0);
            acc = __builtin_amdgcn_mfma_f32_16x16x32_bf16(a[j][0], b1_0, acc, 0, 0, 0);
            acc = __builtin_amdgcn_mfma_f32_16x16x32_bf16(a[j][1], b1_1, acc, 0, 0, 0);
#pragma unroll
            for (int r = 0; r < 4; ++r) {
                const float av = acc[r];
                bestd2[j][r] = fminf(bestd2[j][r], fmaxf(av, bestd[j][r]));
                if (av < bestd[j][r]) { bestd[j][r] = av; besti[j][r] = code0 + col; }
            }
        }
    }

    float lsum = 0.f;
#pragma unroll
    for (int j = 0; j < 4; ++j) {
#pragma unroll
        for (int r = 0; r < 4; ++r) {
            float d1 = bestd[j][r], d2 = bestd2[j][r]; int i1 = besti[j][r];
            for (int m = 1; m <= 8; m <<= 1) {
                const float d1o = __shfl_xor(d1, m, 64);
                const int   i1o = __shfl_xor(i1, m, 64);
                const float d2o = __shfl_xor(d2, m, 64);
                if (d1o < d1 || (d1o == d1 && i1o < i1)) {
                    d2 = fminf(d1, d2o); d1 = d1o; i1 = i1o;
                } else {
                    d2 = fminf(d2, d1o);
                }
            }
            if (col == 0) {                       // C/D row = quad*4 + r
                const int tok = j * 16 + quad * 4 + r;
                out[OFF_IDX + nw + tok] = (float)i1;
                atomicAdd(&s_cnt[i1], 1);
                lsum += d1 + s_x2[w * 64 + tok];  // x2 added for loss only
                if (d2 - d1 < DELTA_) {
                    const int pos = atomicAdd(&wsi[WS_AMBN], 1);
                    wsi[WS_AMB + pos] = nw + tok;
                }
            }
        }
    }
    if (col == 0) atomicAdd(&s_loss, lsum);
    __syncthreads();
    for (int i = t; i < K_; i += 256) {
        const int v = s_cnt[i];
        if (v) atomicAdd(&wsi[WS_CNT + i], v);
    }
    if (t == 0) atomicAdd(&wsf[WS_LOSS], s_loss);
}

// ---------------------------------------------------------------------------
// K1b: exact fp32 rescore of ambiguous tokens; patches idx + counts.
// ---------------------------------------------------------------------------
__global__ __launch_bounds__(256) void k_fixup(const float* __restrict__ embed,
                                               float* __restrict__ out,
                                               const float* __restrict__ wsf,
                                               int* __restrict__ wsi) {
    __shared__ float sx[4][C_];
    const int t = threadIdx.x;
    const int lane = t & 63;
    const int w = t >> 6;
    const int gw = blockIdx.x * 4 + w;
    const int nw = gridDim.x * 4;
    const int cntA = wsi[WS_AMBN];

    for (int a = gw; a < cntA; a += nw) {
        const int n = wsi[WS_AMB + a];
        const float xv = out[OFF_Q + (size_t)n * C_ + lane];  // flat_x row
        sx[w][lane] = xv;
        float x2 = xv * xv;
        for (int m = 1; m <= 32; m <<= 1) x2 += __shfl_xor(x2, m, 64);

        float bd = 3.4e38f; int bi = 0;
        for (int q = 0; q < 8; ++q) {
            const int k = lane + (q << 6);               // ascending per lane
            const float* e = embed + k * C_;
            float d0 = 0.f, d1 = 0.f, d2 = 0.f, d3 = 0.f;
#pragma unroll
            for (int c = 0; c < C_; c += 4) {
                d0 += sx[w][c + 0] * e[c + 0];
                d1 += sx[w][c + 1] * e[c + 1];
                d2 += sx[w][c + 2] * e[c + 2];
                d3 += sx[w][c + 3] * e[c + 3];
            }
            const float dist = x2 + wsf[WS_E2 + k] - 2.f * ((d0 + d1) + (d2 + d3));
            if (dist < bd) { bd = dist; bi = k; }
        }
        for (int m = 1; m <= 32; m <<= 1) {
            const float db = __shfl_xor(bd, m, 64);
            const int   ib = __shfl_xor(bi, m, 64);
            if (db < bd || (db == bd && ib < bi)) { bd = db; bi = ib; }
        }
        if (lane == 0) {
            const int old = (int)out[OFF_IDX + n];
            if (bi != old) {
                out[OFF_IDX + n] = (float)bi;
                atomicAdd(&wsi[WS_CNT + old], -1);
                atomicAdd(&wsi[WS_CNT + bi], 1);
            }
        }
    }
}

// ---------------------------------------------------------------------------
// K2: single block, 512 threads. new_cluster_size, n, perplexity, smoothed,
//     exclusive prefix sum of counts, loss finalize.
// ---------------------------------------------------------------------------
__global__ __launch_bounds__(512) void k_stats(const float* __restrict__ cs,
                                               float* __restrict__ out,
                                               float* __restrict__ wsf,
                                               int* __restrict__ wsi) {
    __shared__ float sf[K_];
    __shared__ int   si[K_];
    const int t = threadIdx.x;

    const int cnt = wsi[WS_CNT + t];
    const float ncs = cs[t] * DECAY_ + ONEM_ * (float)cnt;
    out[OFF_NCS + t] = ncs;

    sf[t] = ncs;
    __syncthreads();
    for (int o = 256; o > 0; o >>= 1) {
        if (t < o) sf[t] += sf[t + o];
        __syncthreads();
    }
    const float n = sf[0];
    __syncthreads();

    const float ap = (float)cnt / (float)N_;
    sf[t] = ap * logf(ap + 1e-10f);
    __syncthreads();
    for (int o = 256; o > 0; o >>= 1) {
        if (t < o) sf[t] += sf[t + o];
        __syncthreads();
    }
    if (t == 0) {
        out[OFF_PERP] = expf(-sf[0]);
        out[OFF_LOSS] = 0.25f * wsf[WS_LOSS] / (float)((long long)N_ * C_);
    }

    wsf[WS_SMOOTH + t] = n * (ncs + ALPHA_) / (n + (float)K_ * ALPHA_);

    si[t] = cnt;
    __syncthreads();
    for (int o = 1; o < K_; o <<= 1) {
        int v = (t >= o) ? si[t - o] : 0;
        __syncthreads();
        si[t] += v;
        __syncthreads();
    }
    wsi[WS_OFFS + t] = si[t] - cnt;
}

// ---------------------------------------------------------------------------
// K3: counting-sort scatter of token ids by code.
// ---------------------------------------------------------------------------
__global__ __launch_bounds__(256) void k_scatter(const float* __restrict__ out,
                                                 int* __restrict__ wsi) {
    const int n = blockIdx.x * 256 + threadIdx.x;
    const int k = (int)out[OFF_IDX + n];
    const int pos = atomicAdd(&wsi[WS_CUR + k], 1);
    wsi[WS_SORT + wsi[WS_OFFS + k] + pos] = n;
}

// ---------------------------------------------------------------------------
// K4: dw partials. Grid = K_*SPLITS one-wave blocks; ids bulk-loaded +
//     shfl-broadcast; row gathers 4 deep; plain coalesced partial stores.
// ---------------------------------------------------------------------------
__global__ __launch_bounds__(64) void k_dw_split(float* __restrict__ out,
                                                 float* __restrict__ wsf,
                                                 const int* __restrict__ wsi) {
    const int lane = threadIdx.x;                 // == channel c
    const int k = blockIdx.x >> 3;
    const int p = blockIdx.x & (SPLITS - 1);
    const int off = wsi[WS_OFFS + k];
    const int cnt = wsi[WS_CNT + k];
    const int chunk = (cnt + SPLITS - 1) >> 3;
    const int j0 = p * chunk;
    const int j1 = min(j0 + chunk, cnt);
    const float* fx = out + OFF_Q;
    const int* sort = wsi + WS_SORT + off;

    float acc = 0.f;
    for (int base = j0; base < j1; base += 64) {
        const int mcnt = min(64, j1 - base);
        int id = 0;
        if (base + lane < j1) id = sort[base + lane];
        int m = 0;
        for (; m + 4 <= mcnt; m += 4) {
            const int t0 = __shfl(id, m + 0, 64);
            const int t1 = __shfl(id, m + 1, 64);
            const int t2 = __shfl(id, m + 2, 64);
            const int t3 = __shfl(id, m + 3, 64);
            const float v0 = fx[(size_t)t0 * C_ + lane];
            const float v1 = fx[(size_t)t1 * C_ + lane];
            const float v2 = fx[(size_t)t2 * C_ + lane];
            const float v3 = fx[(size_t)t3 * C_ + lane];
            acc += (v0 + v1) + (v2 + v3);
        }
        for (; m < mcnt; ++m) {
            const int tk = __shfl(id, m, 64);
            acc += fx[(size_t)tk * C_ + lane];
        }
    }
    wsf[WS_PART + (size_t)blockIdx.x * C_ + lane] = acc;
}

// ---------------------------------------------------------------------------
// K5: reduce SPLITS partials -> dw, then EMA outputs.
// ---------------------------------------------------------------------------
__global__ __launch_bounds__(256) void k_ema(const float* __restrict__ embed_avg,
                                             float* __restrict__ out,
                                             const float* __restrict__ wsf) {
    const int i = blockIdx.x * 256 + threadIdx.x;   // i = k*64 + c
    const int k = i >> 6;
    const int c = i & 63;
    float dw = 0.f;
#pragma unroll
    for (int p = 0; p < SPLITS; ++p)
        dw += wsf[WS_PART + (size_t)(k * SPLITS + p) * C_ + c];
    const float nea = embed_avg[i] * DECAY_ + ONEM_ * dw;
    out[OFF_NEA + i] = nea;
    out[OFF_NEMB + i] = nea / wsf[WS_SMOOTH + k];
}

// ---------------------------------------------------------------------------
// K6: rewrite the quantized region with embed[idx] in [B,C,S] layout.
// ---------------------------------------------------------------------------
__global__ __launch_bounds__(256) void k_quant(const float* __restrict__ embed,
                                               float* __restrict__ out) {
    const int t = threadIdx.x;
    const int n = blockIdx.x * 256 + t;
    const int b = n >> 15;
    const int s = n & (S_ - 1);
    const int base = (b << 21) + s;
    const int k = (int)out[OFF_IDX + n];
    const float4* er = (const float4*)(embed + k * C_);
#pragma unroll
    for (int q = 0; q < 16; ++q) {
        float4 v = er[q];
        out[OFF_Q + base + ((4*q + 0) << 15)] = v.x;
        out[OFF_Q + base + ((4*q + 1) << 15)] = v.y;
        out[OFF_Q + base + ((4*q + 2) << 15)] = v.z;
        out[OFF_Q + base + ((4*q + 3) << 15)] = v.w;
    }
}

extern "C" void kernel_launch(void* const* d_in, const int* in_sizes, int n_in,
                              void* d_out, int out_size, void* d_ws, size_t ws_size,
                              hipStream_t stream) {
    const float* in        = (const float*)d_in[0];
    const float* embed     = (const float*)d_in[1];
    const float* embed_avg = (const float*)d_in[2];
    const float* cs        = (const float*)d_in[3];
    float* out = (float*)d_out;
    float* wsf = (float*)d_ws;
    int*   wsi = (int*)d_ws;

    // zero: loss accum + ambig count + counts + cursors
    hipMemsetAsync(d_ws, 0, (WS_CUR + K_) * sizeof(int), stream);

    k_split   <<<K_ / 4, 256, 0, stream>>>(embed, wsf);
    k_assign  <<<N_ / 256, 256, 0, stream>>>(in, out, wsf, wsi);
    k_fixup   <<<128, 256, 0, stream>>>(embed, out, wsf, wsi);
    k_stats   <<<1, K_, 0, stream>>>(cs, out, wsf, wsi);
    k_scatter <<<N_ / 256, 256, 0, stream>>>(out, wsi);
    k_dw_split<<<K_ * SPLITS, 64, 0, stream>>>(out, wsf, wsi);
    k_ema     <<<K_ * C_ / 256, 256, 0, stream>>>(embed_avg, out, wsf);
    k_quant   <<<N_ / 256, 256, 0, stream>>>(embed, out);
}

// Round 9
// 305.395 us; speedup vs baseline: 1.5625x; 1.0423x over previous
//
#include <hip/hip_runtime.h>
#include <math.h>

typedef __attribute__((ext_vector_type(8))) short s16x8;   // 8 bf16 (4 VGPRs)
typedef __attribute__((ext_vector_type(4))) float f32x4;   // MFMA C/D

// Problem constants
#define B_    4
#define C_    64
#define S_    32768          // 32*32*32 spatial
#define N_    131072         // B_*S_ tokens
#define K_    512            // codebook size
#define SPLITS 8             // blocks per code in k_dw_split
#define DECAY_ 0.99f
#define ONEM_  0.01f
#define ALPHA_ 1e-5f
#define DELTA_ 0.01f         // margin >> 2-split emulation worst-case (~2e-3)

// d_out layout (float32, concatenated in reference return order)
#define OFF_LOSS 0
#define OFF_Q    1
#define OFF_PERP 8388609
#define OFF_IDX  8388610
#define OFF_NEMB 8519682
#define OFF_NCS  8552450
#define OFF_NEA  8552962

// ws layout in 4-byte units (high-water 576016 dwords = 2.25 MB)
#define WS_LOSS   0         // [0] loss accum
#define WS_AMBN   8         // [8] ambiguous-token count
#define WS_CNT    16        // 512 ints
#define WS_CUR    528       // 512 ints
#define WS_OFFS   1040      // 512 ints
#define WS_SMOOTH 1552      // 512 floats
#define WS_E2     2064      // 512 floats (||e||^2)
#define WS_SORT   2576      // 131072 ints
#define WS_PART   133648    // 8*512*64 floats -> ends 395792
#define WS_SPL    395792    // 2-split bf16 table: 2*512*64*2B = 32768 dwords -> ends 428560
#define WS_AMB    444944    // up to 131072 ints -> ends 576016

__device__ __forceinline__ ushort f2bf(float f) {           // RNE fp32 -> bf16
    uint u = __float_as_uint(f);
    u = u + 0x7FFFu + ((u >> 16) & 1u);
    return (ushort)(u >> 16);
}
__device__ __forceinline__ float bf2f(ushort h) {
    return __uint_as_float(((uint)h) << 16);
}

// ---------------------------------------------------------------------------
// K0: split table. B' = -2*embed as 2 bf16 terms (hi, lo), plus ||e||^2.
// ---------------------------------------------------------------------------
__global__ __launch_bounds__(256) void k_split(const float* __restrict__ embed,
                                               float* __restrict__ wsf) {
    const int t = threadIdx.x;
    const int lane = t & 63;
    const int code = blockIdx.x * 4 + (t >> 6);
    const float e = embed[code * C_ + lane];
    const float sc = -2.f * e;
    const ushort h1 = f2bf(sc);
    const ushort h2 = f2bf(sc - bf2f(h1));
    ushort* tab = (ushort*)(wsf + WS_SPL);
    tab[0 * (K_ * C_) + code * C_ + lane] = h1;
    tab[1 * (K_ * C_) + code * C_ + lane] = h2;
    float sq = e * e;
    for (int o = 32; o > 0; o >>= 1) sq += __shfl_down(sq, o, 64);
    if (lane == 0) wsf[WS_E2 + code] = sq;
}

// ---------------------------------------------------------------------------
// K1: MFMA argmin. 4 A-sets (64 tokens) per wave; 2-way split => 8 MFMA per
//     (ct, j) in TERM-MAJOR order (4 independent j-chains back-to-back per
//     term -> MFMA latency hidden). B tiles register double-buffered so the
//     L2 load for ct+1 is in flight during ct's MFMAs. Runner-up margin ->
//     ambiguous list. Writes flat_x + idx + LDS histogram + loss.
// ---------------------------------------------------------------------------
__global__ __launch_bounds__(256, 2) void k_assign(const float* __restrict__ in,
                                                   float* __restrict__ out,
                                                   float* __restrict__ wsf,
                                                   int* __restrict__ wsi) {
    __shared__ float s_e2l[K_];
    __shared__ int   s_cnt[K_];
    __shared__ float s_x2[256];
    __shared__ float s_loss;

    const int t = threadIdx.x;
    const int lane = t & 63;
    const int w = t >> 6;
    const int col = lane & 15;       // A row m / B,C col n
    const int quad = lane >> 4;      // k-chunk for A/B; row-group for C/D

    for (int i = t; i < K_; i += 256) { s_e2l[i] = wsf[WS_E2 + i]; s_cnt[i] = 0; }
    if (t == 0) s_loss = 0.f;

    const int nw = blockIdx.x * 256 + w * 64;   // wave token base (64 tokens)

    // a[j][split][ktile], split 0 = hi, 1 = lo
    s16x8 a[4][2][2];
#pragma unroll
    for (int j = 0; j < 4; ++j) {
        const int n = nw + j * 16 + col;
        const int base = ((n >> 15) << 21) + (n & (S_ - 1));
        float x0[8], x1[8];
#pragma unroll
        for (int q = 0; q < 8; ++q) {
            x0[q] = in[base + ((quad * 8 + q) << 15)];
            x1[q] = in[base + ((32 + quad * 8 + q) << 15)];
        }
        float x2 = 0.f;
#pragma unroll
        for (int q = 0; q < 8; ++q) x2 += x0[q] * x0[q] + x1[q] * x1[q];
        x2 += __shfl_xor(x2, 16, 64);
        x2 += __shfl_xor(x2, 32, 64);
        if (quad == 0) s_x2[w * 64 + j * 16 + col] = x2;

        float4* q0 = (float4*)(out + OFF_Q + (size_t)n * C_ + quad * 8);
        q0[0] = make_float4(x0[0], x0[1], x0[2], x0[3]);
        q0[1] = make_float4(x0[4], x0[5], x0[6], x0[7]);
        float4* q1 = (float4*)(out + OFF_Q + (size_t)n * C_ + 32 + quad * 8);
        q1[0] = make_float4(x1[0], x1[1], x1[2], x1[3]);
        q1[1] = make_float4(x1[4], x1[5], x1[6], x1[7]);

#pragma unroll
        for (int q = 0; q < 8; ++q) {
            ushort h = f2bf(x0[q]); a[j][0][0][q] = (short)h;
            a[j][1][0][q] = (short)f2bf(x0[q] - bf2f(h));
            h = f2bf(x1[q]); a[j][0][1][q] = (short)h;
            a[j][1][1][q] = (short)f2bf(x1[q] - bf2f(h));
        }
    }
    __syncthreads();

    const s16x8* tab = (const s16x8*)(wsf + WS_SPL);  // split stride 4096 s16x8
    float bestd[4][4], bestd2[4][4];
    int   besti[4][4];
#pragma unroll
    for (int j = 0; j < 4; ++j)
#pragma unroll
        for (int r = 0; r < 4; ++r) { bestd[j][r] = 3.4e38f; bestd2[j][r] = 3.4e38f; besti[j][r] = 0; }

    int o = col * 8 + quad;
    s16x8 bh0 = tab[o], bh1 = tab[o + 4];             // hi split, kt0/kt1
    s16x8 bl0 = tab[4096 + o], bl1 = tab[4096 + o + 4];

    for (int ct = 0; ct < 32; ++ct) {
        // prefetch ct+1's B tiles (in flight during this ct's MFMAs)
        s16x8 nh0, nh1, nl0, nl1;
        if (ct < 31) {
            const int on = o + 128;
            nh0 = tab[on];        nh1 = tab[on + 4];
            nl0 = tab[4096 + on]; nl1 = tab[4096 + on + 4];
        }
        const float e2c = s_e2l[ct * 16 + col];
        f32x4 acc[4];
#pragma unroll
        for (int j = 0; j < 4; ++j) acc[j] = (f32x4){e2c, e2c, e2c, e2c};
        // term-major, smallest first; 4 independent chains per term
#pragma unroll
        for (int j = 0; j < 4; ++j) acc[j] = __builtin_amdgcn_mfma_f32_16x16x32_bf16(a[j][1][0], bl0, acc[j], 0, 0, 0);
#pragma unroll
        for (int j = 0; j < 4; ++j) acc[j] = __builtin_amdgcn_mfma_f32_16x16x32_bf16(a[j][1][1], bl1, acc[j], 0, 0, 0);
#pragma unroll
        for (int j = 0; j < 4; ++j) acc[j] = __builtin_amdgcn_mfma_f32_16x16x32_bf16(a[j][1][0], bh0, acc[j], 0, 0, 0);
#pragma unroll
        for (int j = 0; j < 4; ++j) acc[j] = __builtin_amdgcn_mfma_f32_16x16x32_bf16(a[j][1][1], bh1, acc[j], 0, 0, 0);
#pragma unroll
        for (int j = 0; j < 4; ++j) acc[j] = __builtin_amdgcn_mfma_f32_16x16x32_bf16(a[j][0][0], bl0, acc[j], 0, 0, 0);
#pragma unroll
        for (int j = 0; j < 4; ++j) acc[j] = __builtin_amdgcn_mfma_f32_16x16x32_bf16(a[j][0][1], bl1, acc[j], 0, 0, 0);
#pragma unroll
        for (int j = 0; j < 4; ++j) acc[j] = __builtin_amdgcn_mfma_f32_16x16x32_bf16(a[j][0][0], bh0, acc[j], 0, 0, 0);
#pragma unroll
        for (int j = 0; j < 4; ++j) acc[j] = __builtin_amdgcn_mfma_f32_16x16x32_bf16(a[j][0][1], bh1, acc[j], 0, 0, 0);

        const int code = ct * 16 + col;
#pragma unroll
        for (int j = 0; j < 4; ++j) {
#pragma unroll
            for (int r = 0; r < 4; ++r) {
                const float av = acc[j][r];
                bestd2[j][r] = fminf(bestd2[j][r], fmaxf(av, bestd[j][r]));
                if (av < bestd[j][r]) { bestd[j][r] = av; besti[j][r] = code; }
            }
        }
        bh0 = nh0; bh1 = nh1; bl0 = nl0; bl1 = nl1;
        o += 128;
    }

    float lsum = 0.f;
#pragma unroll
    for (int j = 0; j < 4; ++j) {
#pragma unroll
        for (int r = 0; r < 4; ++r) {
            float d1 = bestd[j][r], d2 = bestd2[j][r]; int i1 = besti[j][r];
            for (int m = 1; m <= 8; m <<= 1) {
                const float d1o = __shfl_xor(d1, m, 64);
                const int   i1o = __shfl_xor(i1, m, 64);
                const float d2o = __shfl_xor(d2, m, 64);
                if (d1o < d1 || (d1o == d1 && i1o < i1)) {
                    d2 = fminf(d1, d2o); d1 = d1o; i1 = i1o;
                } else {
                    d2 = fminf(d2, d1o);
                }
            }
            if (col == 0) {                       // C/D row = quad*4 + r
                const int tok = j * 16 + quad * 4 + r;
                out[OFF_IDX + nw + tok] = (float)i1;
                atomicAdd(&s_cnt[i1], 1);
                lsum += d1 + s_x2[w * 64 + tok];  // x2 added for loss only
                if (d2 - d1 < DELTA_) {
                    const int pos = atomicAdd(&wsi[WS_AMBN], 1);
                    wsi[WS_AMB + pos] = nw + tok;
                }
            }
        }
    }
    if (col == 0) atomicAdd(&s_loss, lsum);
    __syncthreads();
    for (int i = t; i < K_; i += 256) {
        const int v = s_cnt[i];
        if (v) atomicAdd(&wsi[WS_CNT + i], v);
    }
    if (t == 0) atomicAdd(&wsf[WS_LOSS], s_loss);
}

// ---------------------------------------------------------------------------
// K1b: exact fp32 rescore of ambiguous tokens; patches idx + counts.
// ---------------------------------------------------------------------------
__global__ __launch_bounds__(256) void k_fixup(const float* __restrict__ embed,
                                               float* __restrict__ out,
                                               const float* __restrict__ wsf,
                                               int* __restrict__ wsi) {
    __shared__ float sx[4][C_];
    const int t = threadIdx.x;
    const int lane = t & 63;
    const int w = t >> 6;
    const int gw = blockIdx.x * 4 + w;
    const int nw = gridDim.x * 4;
    const int cntA = wsi[WS_AMBN];

    for (int a = gw; a < cntA; a += nw) {
        const int n = wsi[WS_AMB + a];
        const float xv = out[OFF_Q + (size_t)n * C_ + lane];  // flat_x row
        sx[w][lane] = xv;
        float x2 = xv * xv;
        for (int m = 1; m <= 32; m <<= 1) x2 += __shfl_xor(x2, m, 64);

        float bd = 3.4e38f; int bi = 0;
        for (int q = 0; q < 8; ++q) {
            const int k = lane + (q << 6);               // ascending per lane
            const float* e = embed + k * C_;
            float d0 = 0.f, d1 = 0.f, d2 = 0.f, d3 = 0.f;
#pragma unroll
            for (int c = 0; c < C_; c += 4) {
                d0 += sx[w][c + 0] * e[c + 0];
                d1 += sx[w][c + 1] * e[c + 1];
                d2 += sx[w][c + 2] * e[c + 2];
                d3 += sx[w][c + 3] * e[c + 3];
            }
            const float dist = x2 + wsf[WS_E2 + k] - 2.f * ((d0 + d1) + (d2 + d3));
            if (dist < bd) { bd = dist; bi = k; }
        }
        for (int m = 1; m <= 32; m <<= 1) {
            const float db = __shfl_xor(bd, m, 64);
            const int   ib = __shfl_xor(bi, m, 64);
            if (db < bd || (db == bd && ib < bi)) { bd = db; bi = ib; }
        }
        if (lane == 0) {
            const int old = (int)out[OFF_IDX + n];
            if (bi != old) {
                out[OFF_IDX + n] = (float)bi;
                atomicAdd(&wsi[WS_CNT + old], -1);
                atomicAdd(&wsi[WS_CNT + bi], 1);
            }
        }
    }
}

// ---------------------------------------------------------------------------
// K2: single block, 512 threads. new_cluster_size, n, perplexity, smoothed,
//     exclusive prefix sum of counts, loss finalize.
// ---------------------------------------------------------------------------
__global__ __launch_bounds__(512) void k_stats(const float* __restrict__ cs,
                                               float* __restrict__ out,
                                               float* __restrict__ wsf,
                                               int* __restrict__ wsi) {
    __shared__ float sf[K_];
    __shared__ int   si[K_];
    const int t = threadIdx.x;

    const int cnt = wsi[WS_CNT + t];
    const float ncs = cs[t] * DECAY_ + ONEM_ * (float)cnt;
    out[OFF_NCS + t] = ncs;

    sf[t] = ncs;
    __syncthreads();
    for (int o = 256; o > 0; o >>= 1) {
        if (t < o) sf[t] += sf[t + o];
        __syncthreads();
    }
    const float n = sf[0];
    __syncthreads();

    const float ap = (float)cnt / (float)N_;
    sf[t] = ap * logf(ap + 1e-10f);
    __syncthreads();
    for (int o = 256; o > 0; o >>= 1) {
        if (t < o) sf[t] += sf[t + o];
        __syncthreads();
    }
    if (t == 0) {
        out[OFF_PERP] = expf(-sf[0]);
        out[OFF_LOSS] = 0.25f * wsf[WS_LOSS] / (float)((long long)N_ * C_);
    }

    wsf[WS_SMOOTH + t] = n * (ncs + ALPHA_) / (n + (float)K_ * ALPHA_);

    si[t] = cnt;
    __syncthreads();
    for (int o = 1; o < K_; o <<= 1) {
        int v = (t >= o) ? si[t - o] : 0;
        __syncthreads();
        si[t] += v;
        __syncthreads();
    }
    wsi[WS_OFFS + t] = si[t] - cnt;
}

// ---------------------------------------------------------------------------
// K3: counting-sort scatter of token ids by code.
// ---------------------------------------------------------------------------
__global__ __launch_bounds__(256) void k_scatter(const float* __restrict__ out,
                                                 int* __restrict__ wsi) {
    const int n = blockIdx.x * 256 + threadIdx.x;
    const int k = (int)out[OFF_IDX + n];
    const int pos = atomicAdd(&wsi[WS_CUR + k], 1);
    wsi[WS_SORT + wsi[WS_OFFS + k] + pos] = n;
}

// ---------------------------------------------------------------------------
// K4: dw partials. Grid = K_*SPLITS one-wave blocks; ids bulk-loaded +
//     shfl-broadcast; row gathers 4 deep; plain coalesced partial stores.
// ---------------------------------------------------------------------------
__global__ __launch_bounds__(64) void k_dw_split(float* __restrict__ out,
                                                 float* __restrict__ wsf,
                                                 const int* __restrict__ wsi) {
    const int lane = threadIdx.x;                 // == channel c
    const int k = blockIdx.x >> 3;
    const int p = blockIdx.x & (SPLITS - 1);
    const int off = wsi[WS_OFFS + k];
    const int cnt = wsi[WS_CNT + k];
    const int chunk = (cnt + SPLITS - 1) >> 3;
    const int j0 = p * chunk;
    const int j1 = min(j0 + chunk, cnt);
    const float* fx = out + OFF_Q;
    const int* sort = wsi + WS_SORT + off;

    float acc = 0.f;
    for (int base = j0; base < j1; base += 64) {
        const int mcnt = min(64, j1 - base);
        int id = 0;
        if (base + lane < j1) id = sort[base + lane];
        int m = 0;
        for (; m + 4 <= mcnt; m += 4) {
            const int t0 = __shfl(id, m + 0, 64);
            const int t1 = __shfl(id, m + 1, 64);
            const int t2 = __shfl(id, m + 2, 64);
            const int t3 = __shfl(id, m + 3, 64);
            const float v0 = fx[(size_t)t0 * C_ + lane];
            const float v1 = fx[(size_t)t1 * C_ + lane];
            const float v2 = fx[(size_t)t2 * C_ + lane];
            const float v3 = fx[(size_t)t3 * C_ + lane];
            acc += (v0 + v1) + (v2 + v3);
        }
        for (; m < mcnt; ++m) {
            const int tk = __shfl(id, m, 64);
            acc += fx[(size_t)tk * C_ + lane];
        }
    }
    wsf[WS_PART + (size_t)blockIdx.x * C_ + lane] = acc;
}

// ---------------------------------------------------------------------------
// K5: reduce SPLITS partials -> dw, then EMA outputs.
// ---------------------------------------------------------------------------
__global__ __launch_bounds__(256) void k_ema(const float* __restrict__ embed_avg,
                                             float* __restrict__ out,
                                             const float* __restrict__ wsf) {
    const int i = blockIdx.x * 256 + threadIdx.x;   // i = k*64 + c
    const int k = i >> 6;
    const int c = i & 63;
    float dw = 0.f;
#pragma unroll
    for (int p = 0; p < SPLITS; ++p)
        dw += wsf[WS_PART + (size_t)(k * SPLITS + p) * C_ + c];
    const float nea = embed_avg[i] * DECAY_ + ONEM_ * dw;
    out[OFF_NEA + i] = nea;
    out[OFF_NEMB + i] = nea / wsf[WS_SMOOTH + k];
}

// ---------------------------------------------------------------------------
// K6: rewrite the quantized region with embed[idx] in [B,C,S] layout.
// ---------------------------------------------------------------------------
__global__ __launch_bounds__(256) void k_quant(const float* __restrict__ embed,
                                               float* __restrict__ out) {
    const int t = threadIdx.x;
    const int n = blockIdx.x * 256 + t;
    const int b = n >> 15;
    const int s = n & (S_ - 1);
    const int base = (b << 21) + s;
    const int k = (int)out[OFF_IDX + n];
    const float4* er = (const float4*)(embed + k * C_);
#pragma unroll
    for (int q = 0; q < 16; ++q) {
        float4 v = er[q];
        out[OFF_Q + base + ((4*q + 0) << 15)] = v.x;
        out[OFF_Q + base + ((4*q + 1) << 15)] = v.y;
        out[OFF_Q + base + ((4*q + 2) << 15)] = v.z;
        out[OFF_Q + base + ((4*q + 3) << 15)] = v.w;
    }
}

extern "C" void kernel_launch(void* const* d_in, const int* in_sizes, int n_in,
                              void* d_out, int out_size, void* d_ws, size_t ws_size,
                              hipStream_t stream) {
    const float* in        = (const float*)d_in[0];
    const float* embed     = (const float*)d_in[1];
    const float* embed_avg = (const float*)d_in[2];
    const float* cs        = (const float*)d_in[3];
    float* out = (float*)d_out;
    float* wsf = (float*)d_ws;
    int*   wsi = (int*)d_ws;

    // zero: loss accum + ambig count + counts + cursors
    hipMemsetAsync(d_ws, 0, (WS_CUR + K_) * sizeof(int), stream);

    k_split   <<<K_ / 4, 256, 0, stream>>>(embed, wsf);
    k_assign  <<<N_ / 256, 256, 0, stream>>>(in, out, wsf, wsi);
    k_fixup   <<<128, 256, 0, stream>>>(embed, out, wsf, wsi);
    k_stats   <<<1, K_, 0, stream>>>(cs, out, wsf, wsi);
    k_scatter <<<N_ / 256, 256, 0, stream>>>(out, wsi);
    k_dw_split<<<K_ * SPLITS, 64, 0, stream>>>(out, wsf, wsi);
    k_ema     <<<K_ * C_ / 256, 256, 0, stream>>>(embed_avg, out, wsf);
    k_quant   <<<N_ / 256, 256, 0, stream>>>(embed, out);
}

// Round 10
// 238.957 us; speedup vs baseline: 1.9969x; 1.2780x over previous
//
#include <hip/hip_runtime.h>
#include <math.h>

typedef __attribute__((ext_vector_type(8))) short s16x8;   // 8 bf16 (4 VGPRs)
typedef __attribute__((ext_vector_type(4))) float f32x4;   // MFMA C/D

// Problem constants
#define B_    4
#define C_    64
#define S_    32768          // 32*32*32 spatial
#define N_    131072         // B_*S_ tokens
#define K_    512            // codebook size
#define SPLITS 8             // blocks per code in k_dw_split
#define DECAY_ 0.99f
#define ONEM_  0.01f
#define ALPHA_ 1e-5f
#define DELTA_ 0.01f         // margin >> 2-split emulation worst-case (~2e-3)

// d_out layout (float32, concatenated in reference return order)
#define OFF_LOSS 0
#define OFF_Q    1
#define OFF_PERP 8388609
#define OFF_IDX  8388610
#define OFF_NEMB 8519682
#define OFF_NCS  8552450
#define OFF_NEA  8552962

// ws layout in 4-byte units (high-water 576016 dwords = 2.25 MB)
#define WS_LOSS   0         // [0] loss accum
#define WS_AMBN   8         // [8] ambiguous-token count
#define WS_CNT    16        // 512 ints
#define WS_CUR    528       // 512 ints
#define WS_OFFS   1040      // 512 ints
#define WS_SMOOTH 1552      // 512 floats
#define WS_E2     2064      // 512 floats (||e||^2)
#define WS_SORT   2576      // 131072 ints
#define WS_PART   133648    // 8*512*64 floats -> ends 395792
#define WS_SPL    395792    // 2-split bf16 table: 2*512*64*2B = 32768 dwords -> ends 428560
#define WS_AMB    444944    // up to 131072 ints -> ends 576016

__device__ __forceinline__ ushort f2bf(float f) {           // RNE fp32 -> bf16
    uint u = __float_as_uint(f);
    u = u + 0x7FFFu + ((u >> 16) & 1u);
    return (ushort)(u >> 16);
}
__device__ __forceinline__ float bf2f(ushort h) {
    return __uint_as_float(((uint)h) << 16);
}

// ---------------------------------------------------------------------------
// K0: split table. B' = -2*embed as 2 bf16 terms (hi, lo), plus ||e||^2.
// ---------------------------------------------------------------------------
__global__ __launch_bounds__(256) void k_split(const float* __restrict__ embed,
                                               float* __restrict__ wsf) {
    const int t = threadIdx.x;
    const int lane = t & 63;
    const int code = blockIdx.x * 4 + (t >> 6);
    const float e = embed[code * C_ + lane];
    const float sc = -2.f * e;
    const ushort h1 = f2bf(sc);
    const ushort h2 = f2bf(sc - bf2f(h1));
    ushort* tab = (ushort*)(wsf + WS_SPL);
    tab[0 * (K_ * C_) + code * C_ + lane] = h1;
    tab[1 * (K_ * C_) + code * C_ + lane] = h2;
    float sq = e * e;
    for (int o = 32; o > 0; o >>= 1) sq += __shfl_down(sq, o, 64);
    if (lane == 0) wsf[WS_E2 + code] = sq;
}

// ---------------------------------------------------------------------------
// K1: MFMA argmin. 4 A-sets (64 tokens) per wave; 2-way split => 8 MFMA per
//     (ct, j) in TERM-MAJOR order; B tiles register double-buffered.
//     Runner-up margin -> ambiguous list. flat_x + idx + histogram + loss.
// ---------------------------------------------------------------------------
__global__ __launch_bounds__(256, 2) void k_assign(const float* __restrict__ in,
                                                   float* __restrict__ out,
                                                   float* __restrict__ wsf,
                                                   int* __restrict__ wsi) {
    __shared__ float s_e2l[K_];
    __shared__ int   s_cnt[K_];
    __shared__ float s_x2[256];
    __shared__ float s_loss;

    const int t = threadIdx.x;
    const int lane = t & 63;
    const int w = t >> 6;
    const int col = lane & 15;       // A row m / B,C col n
    const int quad = lane >> 4;      // k-chunk for A/B; row-group for C/D

    for (int i = t; i < K_; i += 256) { s_e2l[i] = wsf[WS_E2 + i]; s_cnt[i] = 0; }
    if (t == 0) s_loss = 0.f;

    const int nw = blockIdx.x * 256 + w * 64;   // wave token base (64 tokens)

    // a[j][split][ktile], split 0 = hi, 1 = lo
    s16x8 a[4][2][2];
#pragma unroll
    for (int j = 0; j < 4; ++j) {
        const int n = nw + j * 16 + col;
        const int base = ((n >> 15) << 21) + (n & (S_ - 1));
        float x0[8], x1[8];
#pragma unroll
        for (int q = 0; q < 8; ++q) {
            x0[q] = in[base + ((quad * 8 + q) << 15)];
            x1[q] = in[base + ((32 + quad * 8 + q) << 15)];
        }
        float x2 = 0.f;
#pragma unroll
        for (int q = 0; q < 8; ++q) x2 += x0[q] * x0[q] + x1[q] * x1[q];
        x2 += __shfl_xor(x2, 16, 64);
        x2 += __shfl_xor(x2, 32, 64);
        if (quad == 0) s_x2[w * 64 + j * 16 + col] = x2;

        float4* q0 = (float4*)(out + OFF_Q + (size_t)n * C_ + quad * 8);
        q0[0] = make_float4(x0[0], x0[1], x0[2], x0[3]);
        q0[1] = make_float4(x0[4], x0[5], x0[6], x0[7]);
        float4* q1 = (float4*)(out + OFF_Q + (size_t)n * C_ + 32 + quad * 8);
        q1[0] = make_float4(x1[0], x1[1], x1[2], x1[3]);
        q1[1] = make_float4(x1[4], x1[5], x1[6], x1[7]);

#pragma unroll
        for (int q = 0; q < 8; ++q) {
            ushort h = f2bf(x0[q]); a[j][0][0][q] = (short)h;
            a[j][1][0][q] = (short)f2bf(x0[q] - bf2f(h));
            h = f2bf(x1[q]); a[j][0][1][q] = (short)h;
            a[j][1][1][q] = (short)f2bf(x1[q] - bf2f(h));
        }
    }
    __syncthreads();

    const s16x8* tab = (const s16x8*)(wsf + WS_SPL);  // split stride 4096 s16x8
    float bestd[4][4], bestd2[4][4];
    int   besti[4][4];
#pragma unroll
    for (int j = 0; j < 4; ++j)
#pragma unroll
        for (int r = 0; r < 4; ++r) { bestd[j][r] = 3.4e38f; bestd2[j][r] = 3.4e38f; besti[j][r] = 0; }

    int o = col * 8 + quad;
    s16x8 bh0 = tab[o], bh1 = tab[o + 4];             // hi split, kt0/kt1
    s16x8 bl0 = tab[4096 + o], bl1 = tab[4096 + o + 4];

    for (int ct = 0; ct < 32; ++ct) {
        // prefetch ct+1's B tiles (in flight during this ct's MFMAs)
        s16x8 nh0, nh1, nl0, nl1;
        if (ct < 31) {
            const int on = o + 128;
            nh0 = tab[on];        nh1 = tab[on + 4];
            nl0 = tab[4096 + on]; nl1 = tab[4096 + on + 4];
        }
        const float e2c = s_e2l[ct * 16 + col];
        f32x4 acc[4];
#pragma unroll
        for (int j = 0; j < 4; ++j) acc[j] = (f32x4){e2c, e2c, e2c, e2c};
        // term-major, smallest first; 4 independent chains per term
#pragma unroll
        for (int j = 0; j < 4; ++j) acc[j] = __builtin_amdgcn_mfma_f32_16x16x32_bf16(a[j][1][0], bl0, acc[j], 0, 0, 0);
#pragma unroll
        for (int j = 0; j < 4; ++j) acc[j] = __builtin_amdgcn_mfma_f32_16x16x32_bf16(a[j][1][1], bl1, acc[j], 0, 0, 0);
#pragma unroll
        for (int j = 0; j < 4; ++j) acc[j] = __builtin_amdgcn_mfma_f32_16x16x32_bf16(a[j][1][0], bh0, acc[j], 0, 0, 0);
#pragma unroll
        for (int j = 0; j < 4; ++j) acc[j] = __builtin_amdgcn_mfma_f32_16x16x32_bf16(a[j][1][1], bh1, acc[j], 0, 0, 0);
#pragma unroll
        for (int j = 0; j < 4; ++j) acc[j] = __builtin_amdgcn_mfma_f32_16x16x32_bf16(a[j][0][0], bl0, acc[j], 0, 0, 0);
#pragma unroll
        for (int j = 0; j < 4; ++j) acc[j] = __builtin_amdgcn_mfma_f32_16x16x32_bf16(a[j][0][1], bl1, acc[j], 0, 0, 0);
#pragma unroll
        for (int j = 0; j < 4; ++j) acc[j] = __builtin_amdgcn_mfma_f32_16x16x32_bf16(a[j][0][0], bh0, acc[j], 0, 0, 0);
#pragma unroll
        for (int j = 0; j < 4; ++j) acc[j] = __builtin_amdgcn_mfma_f32_16x16x32_bf16(a[j][0][1], bh1, acc[j], 0, 0, 0);

        const int code = ct * 16 + col;
#pragma unroll
        for (int j = 0; j < 4; ++j) {
#pragma unroll
            for (int r = 0; r < 4; ++r) {
                const float av = acc[j][r];
                bestd2[j][r] = fminf(bestd2[j][r], fmaxf(av, bestd[j][r]));
                if (av < bestd[j][r]) { bestd[j][r] = av; besti[j][r] = code; }
            }
        }
        bh0 = nh0; bh1 = nh1; bl0 = nl0; bl1 = nl1;
        o += 128;
    }

    float lsum = 0.f;
#pragma unroll
    for (int j = 0; j < 4; ++j) {
#pragma unroll
        for (int r = 0; r < 4; ++r) {
            float d1 = bestd[j][r], d2 = bestd2[j][r]; int i1 = besti[j][r];
            for (int m = 1; m <= 8; m <<= 1) {
                const float d1o = __shfl_xor(d1, m, 64);
                const int   i1o = __shfl_xor(i1, m, 64);
                const float d2o = __shfl_xor(d2, m, 64);
                if (d1o < d1 || (d1o == d1 && i1o < i1)) {
                    d2 = fminf(d1, d2o); d1 = d1o; i1 = i1o;
                } else {
                    d2 = fminf(d2, d1o);
                }
            }
            if (col == 0) {                       // C/D row = quad*4 + r
                const int tok = j * 16 + quad * 4 + r;
                out[OFF_IDX + nw + tok] = (float)i1;
                atomicAdd(&s_cnt[i1], 1);
                lsum += d1 + s_x2[w * 64 + tok];  // x2 added for loss only
                if (d2 - d1 < DELTA_) {
                    const int pos = atomicAdd(&wsi[WS_AMBN], 1);
                    wsi[WS_AMB + pos] = nw + tok;
                }
            }
        }
    }
    if (col == 0) atomicAdd(&s_loss, lsum);
    __syncthreads();
    for (int i = t; i < K_; i += 256) {
        const int v = s_cnt[i];
        if (v) atomicAdd(&wsi[WS_CNT + i], v);
    }
    if (t == 0) atomicAdd(&wsf[WS_LOSS], s_loss);
}

// ---------------------------------------------------------------------------
// K1b: exact fp32 rescore of ambiguous tokens; patches idx + counts.
// ---------------------------------------------------------------------------
__global__ __launch_bounds__(256) void k_fixup(const float* __restrict__ embed,
                                               float* __restrict__ out,
                                               const float* __restrict__ wsf,
                                               int* __restrict__ wsi) {
    __shared__ float sx[4][C_];
    const int t = threadIdx.x;
    const int lane = t & 63;
    const int w = t >> 6;
    const int gw = blockIdx.x * 4 + w;
    const int nw = gridDim.x * 4;
    const int cntA = wsi[WS_AMBN];

    for (int a = gw; a < cntA; a += nw) {
        const int n = wsi[WS_AMB + a];
        const float xv = out[OFF_Q + (size_t)n * C_ + lane];  // flat_x row
        sx[w][lane] = xv;
        float x2 = xv * xv;
        for (int m = 1; m <= 32; m <<= 1) x2 += __shfl_xor(x2, m, 64);

        float bd = 3.4e38f; int bi = 0;
        for (int q = 0; q < 8; ++q) {
            const int k = lane + (q << 6);               // ascending per lane
            const float* e = embed + k * C_;
            float d0 = 0.f, d1 = 0.f, d2 = 0.f, d3 = 0.f;
#pragma unroll
            for (int c = 0; c < C_; c += 4) {
                d0 += sx[w][c + 0] * e[c + 0];
                d1 += sx[w][c + 1] * e[c + 1];
                d2 += sx[w][c + 2] * e[c + 2];
                d3 += sx[w][c + 3] * e[c + 3];
            }
            const float dist = x2 + wsf[WS_E2 + k] - 2.f * ((d0 + d1) + (d2 + d3));
            if (dist < bd) { bd = dist; bi = k; }
        }
        for (int m = 1; m <= 32; m <<= 1) {
            const float db = __shfl_xor(bd, m, 64);
            const int   ib = __shfl_xor(bi, m, 64);
            if (db < bd || (db == bd && ib < bi)) { bd = db; bi = ib; }
        }
        if (lane == 0) {
            const int old = (int)out[OFF_IDX + n];
            if (bi != old) {
                out[OFF_IDX + n] = (float)bi;
                atomicAdd(&wsi[WS_CNT + old], -1);
                atomicAdd(&wsi[WS_CNT + bi], 1);
            }
        }
    }
}

// ---------------------------------------------------------------------------
// K2: single block, 512 threads. new_cluster_size, n, perplexity, smoothed,
//     exclusive prefix sum of counts, loss finalize.
// ---------------------------------------------------------------------------
__global__ __launch_bounds__(512) void k_stats(const float* __restrict__ cs,
                                               float* __restrict__ out,
                                               float* __restrict__ wsf,
                                               int* __restrict__ wsi) {
    __shared__ float sf[K_];
    __shared__ int   si[K_];
    const int t = threadIdx.x;

    const int cnt = wsi[WS_CNT + t];
    const float ncs = cs[t] * DECAY_ + ONEM_ * (float)cnt;
    out[OFF_NCS + t] = ncs;

    sf[t] = ncs;
    __syncthreads();
    for (int o = 256; o > 0; o >>= 1) {
        if (t < o) sf[t] += sf[t + o];
        __syncthreads();
    }
    const float n = sf[0];
    __syncthreads();

    const float ap = (float)cnt / (float)N_;
    sf[t] = ap * logf(ap + 1e-10f);
    __syncthreads();
    for (int o = 256; o > 0; o >>= 1) {
        if (t < o) sf[t] += sf[t + o];
        __syncthreads();
    }
    if (t == 0) {
        out[OFF_PERP] = expf(-sf[0]);
        out[OFF_LOSS] = 0.25f * wsf[WS_LOSS] / (float)((long long)N_ * C_);
    }

    wsf[WS_SMOOTH + t] = n * (ncs + ALPHA_) / (n + (float)K_ * ALPHA_);

    si[t] = cnt;
    __syncthreads();
    for (int o = 1; o < K_; o <<= 1) {
        int v = (t >= o) ? si[t - o] : 0;
        __syncthreads();
        si[t] += v;
        __syncthreads();
    }
    wsi[WS_OFFS + t] = si[t] - cnt;
}

// ---------------------------------------------------------------------------
// K3: hierarchical counting-sort scatter. One block per 2048 tokens:
//     LDS histogram -> ONE global atomicAdd per (block, code) to reserve a
//     contiguous range (WS_OFFS folded in) -> LDS-cursor scatter.
//     Global atomics: 131072 -> <=32768 with 64-way (not 256-way) collisions.
// ---------------------------------------------------------------------------
#define SCT 2048
__global__ __launch_bounds__(256) void k_scatter(const float* __restrict__ out,
                                                 int* __restrict__ wsi) {
    __shared__ int hc[K_];         // histogram -> reserved global base
    __shared__ int lc[K_];         // local cursor
    __shared__ int codes[SCT];
    const int t = threadIdx.x;
    const int base = blockIdx.x * SCT;

    for (int i = t; i < K_; i += 256) { hc[i] = 0; lc[i] = 0; }
    __syncthreads();
#pragma unroll
    for (int j = 0; j < SCT / 256; ++j) {
        const int k = (int)out[OFF_IDX + base + j * 256 + t];
        codes[j * 256 + t] = k;
        atomicAdd(&hc[k], 1);
    }
    __syncthreads();
    for (int i = t; i < K_; i += 256) {
        const int c = hc[i];
        int gbase = 0;
        if (c > 0) gbase = atomicAdd(&wsi[WS_CUR + i], c);
        hc[i] = wsi[WS_OFFS + i] + gbase;      // absolute base for this block
    }
    __syncthreads();
#pragma unroll
    for (int j = 0; j < SCT / 256; ++j) {
        const int k = codes[j * 256 + t];
        const int pos = atomicAdd(&lc[k], 1);
        wsi[WS_SORT + hc[k] + pos] = base + j * 256 + t;
    }
}

// ---------------------------------------------------------------------------
// K4: dw partials. Grid = K_*SPLITS one-wave blocks; ids bulk-loaded +
//     shfl-broadcast; row gathers 4 deep; plain coalesced partial stores.
// ---------------------------------------------------------------------------
__global__ __launch_bounds__(64) void k_dw_split(float* __restrict__ out,
                                                 float* __restrict__ wsf,
                                                 const int* __restrict__ wsi) {
    const int lane = threadIdx.x;                 // == channel c
    const int k = blockIdx.x >> 3;
    const int p = blockIdx.x & (SPLITS - 1);
    const int off = wsi[WS_OFFS + k];
    const int cnt = wsi[WS_CNT + k];
    const int chunk = (cnt + SPLITS - 1) >> 3;
    const int j0 = p * chunk;
    const int j1 = min(j0 + chunk, cnt);
    const float* fx = out + OFF_Q;
    const int* sort = wsi + WS_SORT + off;

    float acc = 0.f;
    for (int base = j0; base < j1; base += 64) {
        const int mcnt = min(64, j1 - base);
        int id = 0;
        if (base + lane < j1) id = sort[base + lane];
        int m = 0;
        for (; m + 4 <= mcnt; m += 4) {
            const int t0 = __shfl(id, m + 0, 64);
            const int t1 = __shfl(id, m + 1, 64);
            const int t2 = __shfl(id, m + 2, 64);
            const int t3 = __shfl(id, m + 3, 64);
            const float v0 = fx[(size_t)t0 * C_ + lane];
            const float v1 = fx[(size_t)t1 * C_ + lane];
            const float v2 = fx[(size_t)t2 * C_ + lane];
            const float v3 = fx[(size_t)t3 * C_ + lane];
            acc += (v0 + v1) + (v2 + v3);
        }
        for (; m < mcnt; ++m) {
            const int tk = __shfl(id, m, 64);
            acc += fx[(size_t)tk * C_ + lane];
        }
    }
    wsf[WS_PART + (size_t)blockIdx.x * C_ + lane] = acc;
}

// ---------------------------------------------------------------------------
// K5: reduce SPLITS partials -> dw, then EMA outputs.
// ---------------------------------------------------------------------------
__global__ __launch_bounds__(256) void k_ema(const float* __restrict__ embed_avg,
                                             float* __restrict__ out,
                                             const float* __restrict__ wsf) {
    const int i = blockIdx.x * 256 + threadIdx.x;   // i = k*64 + c
    const int k = i >> 6;
    const int c = i & 63;
    float dw = 0.f;
#pragma unroll
    for (int p = 0; p < SPLITS; ++p)
        dw += wsf[WS_PART + (size_t)(k * SPLITS + p) * C_ + c];
    const float nea = embed_avg[i] * DECAY_ + ONEM_ * dw;
    out[OFF_NEA + i] = nea;
    out[OFF_NEMB + i] = nea / wsf[WS_SMOOTH + k];
}

// ---------------------------------------------------------------------------
// K6: rewrite the quantized region with embed[idx] in [B,C,S] layout.
// ---------------------------------------------------------------------------
__global__ __launch_bounds__(256) void k_quant(const float* __restrict__ embed,
                                               float* __restrict__ out) {
    const int t = threadIdx.x;
    const int n = blockIdx.x * 256 + t;
    const int b = n >> 15;
    const int s = n & (S_ - 1);
    const int base = (b << 21) + s;
    const int k = (int)out[OFF_IDX + n];
    const float4* er = (const float4*)(embed + k * C_);
#pragma unroll
    for (int q = 0; q < 16; ++q) {
        float4 v = er[q];
        out[OFF_Q + base + ((4*q + 0) << 15)] = v.x;
        out[OFF_Q + base + ((4*q + 1) << 15)] = v.y;
        out[OFF_Q + base + ((4*q + 2) << 15)] = v.z;
        out[OFF_Q + base + ((4*q + 3) << 15)] = v.w;
    }
}

extern "C" void kernel_launch(void* const* d_in, const int* in_sizes, int n_in,
                              void* d_out, int out_size, void* d_ws, size_t ws_size,
                              hipStream_t stream) {
    const float* in        = (const float*)d_in[0];
    const float* embed     = (const float*)d_in[1];
    const float* embed_avg = (const float*)d_in[2];
    const float* cs        = (const float*)d_in[3];
    float* out = (float*)d_out;
    float* wsf = (float*)d_ws;
    int*   wsi = (int*)d_ws;

    // zero: loss accum + ambig count + counts + cursors
    hipMemsetAsync(d_ws, 0, (WS_CUR + K_) * sizeof(int), stream);

    k_split   <<<K_ / 4, 256, 0, stream>>>(embed, wsf);
    k_assign  <<<N_ / 256, 256, 0, stream>>>(in, out, wsf, wsi);
    k_fixup   <<<128, 256, 0, stream>>>(embed, out, wsf, wsi);
    k_stats   <<<1, K_, 0, stream>>>(cs, out, wsf, wsi);
    k_scatter <<<N_ / SCT, 256, 0, stream>>>(out, wsi);
    k_dw_split<<<K_ * SPLITS, 64, 0, stream>>>(out, wsf, wsi);
    k_ema     <<<K_ * C_ / 256, 256, 0, stream>>>(embed_avg, out, wsf);
    k_quant   <<<N_ / 256, 256, 0, stream>>>(embed, out);
}

// Round 11
// 223.097 us; speedup vs baseline: 2.1388x; 1.0711x over previous
//
#include <hip/hip_runtime.h>
#include <math.h>

typedef __attribute__((ext_vector_type(8))) short s16x8;   // 8 bf16 (4 VGPRs)
typedef __attribute__((ext_vector_type(4))) float f32x4;   // MFMA C/D

// Problem constants
#define B_    4
#define C_    64
#define S_    32768          // 32*32*32 spatial
#define N_    131072         // B_*S_ tokens
#define K_    512            // codebook size
#define SPLITS 8             // blocks per code in k_dw_split
#define DECAY_ 0.99f
#define ONEM_  0.01f
#define ALPHA_ 1e-5f
#define DELTA_ 0.01f         // margin >> 2-split emulation worst-case (~2e-3)
#define AMB_CAP 65536        // ambiguous-list capacity (expected ~3e3)

// d_out layout (float32, concatenated in reference return order)
#define OFF_LOSS 0
#define OFF_Q    1
#define OFF_PERP 8388609
#define OFF_IDX  8388610
#define OFF_NEMB 8519682
#define OFF_NCS  8552450
#define OFF_NEA  8552962

// ws layout in 4-byte units (high-water 543248 dwords = 2.07 MB < proven 2.25 MB)
#define WS_LOSS   0         // [0] loss accum
#define WS_AMBN   8         // [8] ambiguous-token count
#define WS_CNT    16        // 512 ints
#define WS_CUR    528       // 512 ints
#define WS_OFFS   1040      // 512 ints
#define WS_SMOOTH 1552      // 512 floats
#define WS_E2     2064      // 512 floats (||e||^2)
#define WS_SORT   2576      // 131072 ints
#define WS_PART   133648    // 8*512*64 floats -> ends 395792
#define WS_SPL    395792    // 2-split bf16 table -> ends 428560
#define WS_AMB    444944    // AMB_CAP ints -> ends 510480
#define WS_ET     510480    // embed^T 64x512 fp32 -> ends 543248

__device__ __forceinline__ ushort f2bf(float f) {           // RNE fp32 -> bf16
    uint u = __float_as_uint(f);
    u = u + 0x7FFFu + ((u >> 16) & 1u);
    return (ushort)(u >> 16);
}
__device__ __forceinline__ float bf2f(ushort h) {
    return __uint_as_float(((uint)h) << 16);
}

// ---------------------------------------------------------------------------
// K0: split table (B' = -2*embed as 2 bf16 terms), ||e||^2, and embed^T
//     (64x512 fp32) for the coalesced fixup.
// ---------------------------------------------------------------------------
__global__ __launch_bounds__(256) void k_split(const float* __restrict__ embed,
                                               float* __restrict__ wsf) {
    const int t = threadIdx.x;
    const int lane = t & 63;
    const int code = blockIdx.x * 4 + (t >> 6);
    const float e = embed[code * C_ + lane];
    const float sc = -2.f * e;
    const ushort h1 = f2bf(sc);
    const ushort h2 = f2bf(sc - bf2f(h1));
    ushort* tab = (ushort*)(wsf + WS_SPL);
    tab[0 * (K_ * C_) + code * C_ + lane] = h1;
    tab[1 * (K_ * C_) + code * C_ + lane] = h2;
    wsf[WS_ET + lane * K_ + code] = e;              // embed^T
    float sq = e * e;
    for (int o = 32; o > 0; o >>= 1) sq += __shfl_down(sq, o, 64);
    if (lane == 0) wsf[WS_E2 + code] = sq;
}

// ---------------------------------------------------------------------------
// K1: MFMA argmin. 4 A-sets (64 tokens) per wave; 2-way split => 8 MFMA per
//     (ct, j) in TERM-MAJOR order; B tiles register double-buffered.
//     Runner-up margin -> ambiguous list. flat_x + idx + histogram + loss.
// ---------------------------------------------------------------------------
__global__ __launch_bounds__(256, 2) void k_assign(const float* __restrict__ in,
                                                   float* __restrict__ out,
                                                   float* __restrict__ wsf,
                                                   int* __restrict__ wsi) {
    __shared__ float s_e2l[K_];
    __shared__ int   s_cnt[K_];
    __shared__ float s_x2[256];
    __shared__ float s_loss;

    const int t = threadIdx.x;
    const int lane = t & 63;
    const int w = t >> 6;
    const int col = lane & 15;       // A row m / B,C col n
    const int quad = lane >> 4;      // k-chunk for A/B; row-group for C/D

    for (int i = t; i < K_; i += 256) { s_e2l[i] = wsf[WS_E2 + i]; s_cnt[i] = 0; }
    if (t == 0) s_loss = 0.f;

    const int nw = blockIdx.x * 256 + w * 64;   // wave token base (64 tokens)

    // a[j][split][ktile], split 0 = hi, 1 = lo
    s16x8 a[4][2][2];
#pragma unroll
    for (int j = 0; j < 4; ++j) {
        const int n = nw + j * 16 + col;
        const int base = ((n >> 15) << 21) + (n & (S_ - 1));
        float x0[8], x1[8];
#pragma unroll
        for (int q = 0; q < 8; ++q) {
            x0[q] = in[base + ((quad * 8 + q) << 15)];
            x1[q] = in[base + ((32 + quad * 8 + q) << 15)];
        }
        float x2 = 0.f;
#pragma unroll
        for (int q = 0; q < 8; ++q) x2 += x0[q] * x0[q] + x1[q] * x1[q];
        x2 += __shfl_xor(x2, 16, 64);
        x2 += __shfl_xor(x2, 32, 64);
        if (quad == 0) s_x2[w * 64 + j * 16 + col] = x2;

        float4* q0 = (float4*)(out + OFF_Q + (size_t)n * C_ + quad * 8);
        q0[0] = make_float4(x0[0], x0[1], x0[2], x0[3]);
        q0[1] = make_float4(x0[4], x0[5], x0[6], x0[7]);
        float4* q1 = (float4*)(out + OFF_Q + (size_t)n * C_ + 32 + quad * 8);
        q1[0] = make_float4(x1[0], x1[1], x1[2], x1[3]);
        q1[1] = make_float4(x1[4], x1[5], x1[6], x1[7]);

#pragma unroll
        for (int q = 0; q < 8; ++q) {
            ushort h = f2bf(x0[q]); a[j][0][0][q] = (short)h;
            a[j][1][0][q] = (short)f2bf(x0[q] - bf2f(h));
            h = f2bf(x1[q]); a[j][0][1][q] = (short)h;
            a[j][1][1][q] = (short)f2bf(x1[q] - bf2f(h));
        }
    }
    __syncthreads();

    const s16x8* tab = (const s16x8*)(wsf + WS_SPL);  // split stride 4096 s16x8
    float bestd[4][4], bestd2[4][4];
    int   besti[4][4];
#pragma unroll
    for (int j = 0; j < 4; ++j)
#pragma unroll
        for (int r = 0; r < 4; ++r) { bestd[j][r] = 3.4e38f; bestd2[j][r] = 3.4e38f; besti[j][r] = 0; }

    int o = col * 8 + quad;
    s16x8 bh0 = tab[o], bh1 = tab[o + 4];             // hi split, kt0/kt1
    s16x8 bl0 = tab[4096 + o], bl1 = tab[4096 + o + 4];

    for (int ct = 0; ct < 32; ++ct) {
        // prefetch ct+1's B tiles (in flight during this ct's MFMAs)
        s16x8 nh0, nh1, nl0, nl1;
        if (ct < 31) {
            const int on = o + 128;
            nh0 = tab[on];        nh1 = tab[on + 4];
            nl0 = tab[4096 + on]; nl1 = tab[4096 + on + 4];
        }
        const float e2c = s_e2l[ct * 16 + col];
        f32x4 acc[4];
#pragma unroll
        for (int j = 0; j < 4; ++j) acc[j] = (f32x4){e2c, e2c, e2c, e2c};
        // term-major, smallest first; 4 independent chains per term
#pragma unroll
        for (int j = 0; j < 4; ++j) acc[j] = __builtin_amdgcn_mfma_f32_16x16x32_bf16(a[j][1][0], bl0, acc[j], 0, 0, 0);
#pragma unroll
        for (int j = 0; j < 4; ++j) acc[j] = __builtin_amdgcn_mfma_f32_16x16x32_bf16(a[j][1][1], bl1, acc[j], 0, 0, 0);
#pragma unroll
        for (int j = 0; j < 4; ++j) acc[j] = __builtin_amdgcn_mfma_f32_16x16x32_bf16(a[j][1][0], bh0, acc[j], 0, 0, 0);
#pragma unroll
        for (int j = 0; j < 4; ++j) acc[j] = __builtin_amdgcn_mfma_f32_16x16x32_bf16(a[j][1][1], bh1, acc[j], 0, 0, 0);
#pragma unroll
        for (int j = 0; j < 4; ++j) acc[j] = __builtin_amdgcn_mfma_f32_16x16x32_bf16(a[j][0][0], bl0, acc[j], 0, 0, 0);
#pragma unroll
        for (int j = 0; j < 4; ++j) acc[j] = __builtin_amdgcn_mfma_f32_16x16x32_bf16(a[j][0][1], bl1, acc[j], 0, 0, 0);
#pragma unroll
        for (int j = 0; j < 4; ++j) acc[j] = __builtin_amdgcn_mfma_f32_16x16x32_bf16(a[j][0][0], bh0, acc[j], 0, 0, 0);
#pragma unroll
        for (int j = 0; j < 4; ++j) acc[j] = __builtin_amdgcn_mfma_f32_16x16x32_bf16(a[j][0][1], bh1, acc[j], 0, 0, 0);

        const int code = ct * 16 + col;
#pragma unroll
        for (int j = 0; j < 4; ++j) {
#pragma unroll
            for (int r = 0; r < 4; ++r) {
                const float av = acc[j][r];
                bestd2[j][r] = fminf(bestd2[j][r], fmaxf(av, bestd[j][r]));
                if (av < bestd[j][r]) { bestd[j][r] = av; besti[j][r] = code; }
            }
        }
        bh0 = nh0; bh1 = nh1; bl0 = nl0; bl1 = nl1;
        o += 128;
    }

    float lsum = 0.f;
#pragma unroll
    for (int j = 0; j < 4; ++j) {
#pragma unroll
        for (int r = 0; r < 4; ++r) {
            float d1 = bestd[j][r], d2 = bestd2[j][r]; int i1 = besti[j][r];
            for (int m = 1; m <= 8; m <<= 1) {
                const float d1o = __shfl_xor(d1, m, 64);
                const int   i1o = __shfl_xor(i1, m, 64);
                const float d2o = __shfl_xor(d2, m, 64);
                if (d1o < d1 || (d1o == d1 && i1o < i1)) {
                    d2 = fminf(d1, d2o); d1 = d1o; i1 = i1o;
                } else {
                    d2 = fminf(d2, d1o);
                }
            }
            if (col == 0) {                       // C/D row = quad*4 + r
                const int tok = j * 16 + quad * 4 + r;
                out[OFF_IDX + nw + tok] = (float)i1;
                atomicAdd(&s_cnt[i1], 1);
                lsum += d1 + s_x2[w * 64 + tok];  // x2 added for loss only
                if (d2 - d1 < DELTA_) {
                    const int pos = atomicAdd(&wsi[WS_AMBN], 1);
                    if (pos < AMB_CAP) wsi[WS_AMB + pos] = nw + tok;
                }
            }
        }
    }
    if (col == 0) atomicAdd(&s_loss, lsum);
    __syncthreads();
    for (int i = t; i < K_; i += 256) {
        const int v = s_cnt[i];
        if (v) atomicAdd(&wsi[WS_CNT + i], v);
    }
    if (t == 0) atomicAdd(&wsf[WS_LOSS], s_loss);
}

// ---------------------------------------------------------------------------
// K1b: exact fp32 rescore of ambiguous tokens via embed^T (COALESCED: lanes
//      read consecutive codes). Patches idx + counts.
// ---------------------------------------------------------------------------
__global__ __launch_bounds__(256) void k_fixup(float* __restrict__ out,
                                               const float* __restrict__ wsf,
                                               int* __restrict__ wsi) {
    __shared__ float sx[4][C_];
    const int t = threadIdx.x;
    const int lane = t & 63;
    const int w = t >> 6;
    const int gw = blockIdx.x * 4 + w;
    const int nw = gridDim.x * 4;
    int cntA = wsi[WS_AMBN];
    if (cntA > AMB_CAP) cntA = AMB_CAP;
    const float* eT = wsf + WS_ET;

    for (int a = gw; a < cntA; a += nw) {
        const int n = wsi[WS_AMB + a];
        const float xv = out[OFF_Q + (size_t)n * C_ + lane];  // flat_x row
        sx[w][lane] = xv;
        float x2 = xv * xv;
        for (int m = 1; m <= 32; m <<= 1) x2 += __shfl_xor(x2, m, 64);

        float bd = 3.4e38f; int bi = 0;
#pragma unroll 2
        for (int q = 0; q < 8; ++q) {
            const int k = (q << 6) + lane;               // ascending per lane
            float d0 = 0.f, d1 = 0.f, d2 = 0.f, d3 = 0.f;
#pragma unroll
            for (int c = 0; c < C_; c += 4) {
                d0 += sx[w][c + 0] * eT[(c + 0) * K_ + k];  // coalesced 256 B
                d1 += sx[w][c + 1] * eT[(c + 1) * K_ + k];
                d2 += sx[w][c + 2] * eT[(c + 2) * K_ + k];
                d3 += sx[w][c + 3] * eT[(c + 3) * K_ + k];
            }
            const float dist = x2 + wsf[WS_E2 + k] - 2.f * ((d0 + d1) + (d2 + d3));
            if (dist < bd) { bd = dist; bi = k; }
        }
        for (int m = 1; m <= 32; m <<= 1) {
            const float db = __shfl_xor(bd, m, 64);
            const int   ib = __shfl_xor(bi, m, 64);
            if (db < bd || (db == bd && ib < bi)) { bd = db; bi = ib; }
        }
        if (lane == 0) {
            const int old = (int)out[OFF_IDX + n];
            if (bi != old) {
                out[OFF_IDX + n] = (float)bi;
                atomicAdd(&wsi[WS_CNT + old], -1);
                atomicAdd(&wsi[WS_CNT + bi], 1);
            }
        }
    }
}

// ---------------------------------------------------------------------------
// K2: single block, 512 threads. new_cluster_size, n, perplexity, smoothed,
//     exclusive prefix sum of counts, loss finalize.
// ---------------------------------------------------------------------------
__global__ __launch_bounds__(512) void k_stats(const float* __restrict__ cs,
                                               float* __restrict__ out,
                                               float* __restrict__ wsf,
                                               int* __restrict__ wsi) {
    __shared__ float sf[K_];
    __shared__ int   si[K_];
    const int t = threadIdx.x;

    const int cnt = wsi[WS_CNT + t];
    const float ncs = cs[t] * DECAY_ + ONEM_ * (float)cnt;
    out[OFF_NCS + t] = ncs;

    sf[t] = ncs;
    __syncthreads();
    for (int o = 256; o > 0; o >>= 1) {
        if (t < o) sf[t] += sf[t + o];
        __syncthreads();
    }
    const float n = sf[0];
    __syncthreads();

    const float ap = (float)cnt / (float)N_;
    sf[t] = ap * logf(ap + 1e-10f);
    __syncthreads();
    for (int o = 256; o > 0; o >>= 1) {
        if (t < o) sf[t] += sf[t + o];
        __syncthreads();
    }
    if (t == 0) {
        out[OFF_PERP] = expf(-sf[0]);
        out[OFF_LOSS] = 0.25f * wsf[WS_LOSS] / (float)((long long)N_ * C_);
    }

    wsf[WS_SMOOTH + t] = n * (ncs + ALPHA_) / (n + (float)K_ * ALPHA_);

    si[t] = cnt;
    __syncthreads();
    for (int o = 1; o < K_; o <<= 1) {
        int v = (t >= o) ? si[t - o] : 0;
        __syncthreads();
        si[t] += v;
        __syncthreads();
    }
    wsi[WS_OFFS + t] = si[t] - cnt;
}

// ---------------------------------------------------------------------------
// K3: hierarchical counting-sort scatter (R10): LDS histogram -> one global
//     range-reserve atomic per (block, code) -> LDS-cursor scatter.
// ---------------------------------------------------------------------------
#define SCT 2048
__global__ __launch_bounds__(256) void k_scatter(const float* __restrict__ out,
                                                 int* __restrict__ wsi) {
    __shared__ int hc[K_];         // histogram -> reserved global base
    __shared__ int lc[K_];         // local cursor
    __shared__ int codes[SCT];
    const int t = threadIdx.x;
    const int base = blockIdx.x * SCT;

    for (int i = t; i < K_; i += 256) { hc[i] = 0; lc[i] = 0; }
    __syncthreads();
#pragma unroll
    for (int j = 0; j < SCT / 256; ++j) {
        const int k = (int)out[OFF_IDX + base + j * 256 + t];
        codes[j * 256 + t] = k;
        atomicAdd(&hc[k], 1);
    }
    __syncthreads();
    for (int i = t; i < K_; i += 256) {
        const int c = hc[i];
        int gbase = 0;
        if (c > 0) gbase = atomicAdd(&wsi[WS_CUR + i], c);
        hc[i] = wsi[WS_OFFS + i] + gbase;      // absolute base for this block
    }
    __syncthreads();
#pragma unroll
    for (int j = 0; j < SCT / 256; ++j) {
        const int k = codes[j * 256 + t];
        const int pos = atomicAdd(&lc[k], 1);
        wsi[WS_SORT + hc[k] + pos] = base + j * 256 + t;
    }
}

// ---------------------------------------------------------------------------
// K4: dw partials. Grid = K_*SPLITS one-wave blocks; ids bulk-loaded +
//     shfl-broadcast; row gathers 4 deep; plain coalesced partial stores.
// ---------------------------------------------------------------------------
__global__ __launch_bounds__(64) void k_dw_split(float* __restrict__ out,
                                                 float* __restrict__ wsf,
                                                 const int* __restrict__ wsi) {
    const int lane = threadIdx.x;                 // == channel c
    const int k = blockIdx.x >> 3;
    const int p = blockIdx.x & (SPLITS - 1);
    const int off = wsi[WS_OFFS + k];
    const int cnt = wsi[WS_CNT + k];
    const int chunk = (cnt + SPLITS - 1) >> 3;
    const int j0 = p * chunk;
    const int j1 = min(j0 + chunk, cnt);
    const float* fx = out + OFF_Q;
    const int* sort = wsi + WS_SORT + off;

    float acc = 0.f;
    for (int base = j0; base < j1; base += 64) {
        const int mcnt = min(64, j1 - base);
        int id = 0;
        if (base + lane < j1) id = sort[base + lane];
        int m = 0;
        for (; m + 4 <= mcnt; m += 4) {
            const int t0 = __shfl(id, m + 0, 64);
            const int t1 = __shfl(id, m + 1, 64);
            const int t2 = __shfl(id, m + 2, 64);
            const int t3 = __shfl(id, m + 3, 64);
            const float v0 = fx[(size_t)t0 * C_ + lane];
            const float v1 = fx[(size_t)t1 * C_ + lane];
            const float v2 = fx[(size_t)t2 * C_ + lane];
            const float v3 = fx[(size_t)t3 * C_ + lane];
            acc += (v0 + v1) + (v2 + v3);
        }
        for (; m < mcnt; ++m) {
            const int tk = __shfl(id, m, 64);
            acc += fx[(size_t)tk * C_ + lane];
        }
    }
    wsf[WS_PART + (size_t)blockIdx.x * C_ + lane] = acc;
}

// ---------------------------------------------------------------------------
// K5: reduce SPLITS partials -> dw, then EMA outputs.
// ---------------------------------------------------------------------------
__global__ __launch_bounds__(256) void k_ema(const float* __restrict__ embed_avg,
                                             float* __restrict__ out,
                                             const float* __restrict__ wsf) {
    const int i = blockIdx.x * 256 + threadIdx.x;   // i = k*64 + c
    const int k = i >> 6;
    const int c = i & 63;
    float dw = 0.f;
#pragma unroll
    for (int p = 0; p < SPLITS; ++p)
        dw += wsf[WS_PART + (size_t)(k * SPLITS + p) * C_ + c];
    const float nea = embed_avg[i] * DECAY_ + ONEM_ * dw;
    out[OFF_NEA + i] = nea;
    out[OFF_NEMB + i] = nea / wsf[WS_SMOOTH + k];
}

// ---------------------------------------------------------------------------
// K6: rewrite the quantized region with embed[idx] in [B,C,S] layout.
// ---------------------------------------------------------------------------
__global__ __launch_bounds__(256) void k_quant(const float* __restrict__ embed,
                                               float* __restrict__ out) {
    const int t = threadIdx.x;
    const int n = blockIdx.x * 256 + t;
    const int b = n >> 15;
    const int s = n & (S_ - 1);
    const int base = (b << 21) + s;
    const int k = (int)out[OFF_IDX + n];
    const float4* er = (const float4*)(embed + k * C_);
#pragma unroll
    for (int q = 0; q < 16; ++q) {
        float4 v = er[q];
        out[OFF_Q + base + ((4*q + 0) << 15)] = v.x;
        out[OFF_Q + base + ((4*q + 1) << 15)] = v.y;
        out[OFF_Q + base + ((4*q + 2) << 15)] = v.z;
        out[OFF_Q + base + ((4*q + 3) << 15)] = v.w;
    }
}

extern "C" void kernel_launch(void* const* d_in, const int* in_sizes, int n_in,
                              void* d_out, int out_size, void* d_ws, size_t ws_size,
                              hipStream_t stream) {
    const float* in        = (const float*)d_in[0];
    const float* embed     = (const float*)d_in[1];
    const float* embed_avg = (const float*)d_in[2];
    const float* cs        = (const float*)d_in[3];
    float* out = (float*)d_out;
    float* wsf = (float*)d_ws;
    int*   wsi = (int*)d_ws;

    // zero: loss accum + ambig count + counts + cursors
    hipMemsetAsync(d_ws, 0, (WS_CUR + K_) * sizeof(int), stream);

    k_split   <<<K_ / 4, 256, 0, stream>>>(embed, wsf);
    k_assign  <<<N_ / 256, 256, 0, stream>>>(in, out, wsf, wsi);
    k_fixup   <<<256, 256, 0, stream>>>(out, wsf, wsi);
    k_stats   <<<1, K_, 0, stream>>>(cs, out, wsf, wsi);
    k_scatter <<<N_ / SCT, 256, 0, stream>>>(out, wsi);
    k_dw_split<<<K_ * SPLITS, 64, 0, stream>>>(out, wsf, wsi);
    k_ema     <<<K_ * C_ / 256, 256, 0, stream>>>(embed_avg, out, wsf);
    k_quant   <<<N_ / 256, 256, 0, stream>>>(embed, out);
}